// Round 2
// baseline (6134.016 us; speedup 1.0000x reference)
//
#include <hip/hip_runtime.h>
#include <math.h>

constexpr int LL  = 5;
constexpr int BB  = 4;
constexpr int NN  = 16384;
constexpr int HH  = 8;
constexpr int DHH = 32;
constexpr int GG  = 32;
constexpr int HID = 256;
constexpr int NT  = BB * NN;           // 65536 tokens
constexpr int WSEG = HID * HID + 2 * HID;  // 66048 floats per prepped matrix

__device__ __forceinline__ float gelu_f(float x) {
    return x * 0.5f * (1.0f + erff(x * 0.70710678118654752f));
}

// ---------------------------------------------------------------------------
// Prep: W' = g[k]*W[k,c]; u[c] = sum_k g[k]W[k,c]; cst[c] = sum_k b[k]W[k,c] + bias[c]
// grid = 10 blocks (layer*2 + {px, mlp1}), 256 threads
// ---------------------------------------------------------------------------
__global__ __launch_bounds__(256) void k_wprep(
    const float* __restrict__ px_w, const float* __restrict__ px_b,
    const float* __restrict__ ln1_g, const float* __restrict__ ln1_b,
    const float* __restrict__ mlp_w1, const float* __restrict__ mlp_b1,
    const float* __restrict__ ln2_g, const float* __restrict__ ln2_b,
    float* __restrict__ wp)
{
    int bid = blockIdx.x;
    int i = bid >> 1, which = bid & 1;
    const float *W, *g, *bln, *bias;
    if (which == 0) { W = px_w  + (size_t)i*HID*HID; g = ln1_g + i*HID; bln = ln1_b + i*HID; bias = px_b  + i*HID; }
    else            { W = mlp_w1+ (size_t)i*HID*HID; g = ln2_g + i*HID; bln = ln2_b + i*HID; bias = mlp_b1+ i*HID; }
    float* dst = wp + (size_t)bid * WSEG;
    float* u   = dst + HID*HID;
    float* cst = u + HID;
    int c = threadIdx.x;
    float au = 0.f, ac = 0.f;
    #pragma unroll 8
    for (int k = 0; k < HID; ++k) {
        float w  = W[k*HID + c];
        float gw = g[k] * w;
        dst[k*HID + c] = gw;
        au += gw;
        ac += bln[k] * w;
    }
    u[c] = au;
    cst[c] = ac + bias[c];
}

// ---------------------------------------------------------------------------
// Row stats (mean, rstd) over HID=256 for all NT tokens. grid = NT/64.
// ---------------------------------------------------------------------------
__global__ __launch_bounds__(256) void k_stats(
    const float* __restrict__ src, float* __restrict__ mu, float* __restrict__ rstd)
{
    int m0 = blockIdx.x * 64;
    int tid = threadIdx.x;
    int ml = tid >> 4, q = tid & 15;
    for (int it = 0; it < 4; ++it) {
        int m = m0 + it*16 + ml;
        const float* p = src + (size_t)m*HID + q*16;
        float s = 0.f, ss = 0.f;
        #pragma unroll
        for (int j = 0; j < 4; ++j) {
            float4 v = *(const float4*)(p + j*4);
            s  += v.x + v.y + v.z + v.w;
            ss += v.x*v.x + v.y*v.y + v.z*v.z + v.w*v.w;
        }
        #pragma unroll
        for (int off = 8; off >= 1; off >>= 1) {
            s  += __shfl_xor(s, off);
            ss += __shfl_xor(ss, off);
        }
        if (q == 0) {
            float mm = s * (1.f/HID);
            float vv = ss * (1.f/HID) - mm*mm;
            mu[m] = mm;
            rstd[m] = rsqrtf(vv + 1e-5f);
        }
    }
}

__global__ __launch_bounds__(256) void k_zero(float* __restrict__ p, int n)
{
    int i = blockIdx.x * 256 + threadIdx.x;
    if (i < n) p[i] = 0.f;
}

// ---------------------------------------------------------------------------
// Preprocess MLP: fx = gelu(x@pre_w1+b1)@pre_w2 + b2 + placeholder + cond_emb
// K = 512, tile 64 tokens x 256 channels. grid = NT/64.
// ---------------------------------------------------------------------------
__global__ __launch_bounds__(256) void k_pre(
    const float* __restrict__ x, const float* __restrict__ condition,
    const float* __restrict__ pre_w1, const float* __restrict__ pre_b1,
    const float* __restrict__ pre_w2, const float* __restrict__ pre_b2,
    const float* __restrict__ placeholder, const float* __restrict__ emb_w,
    const float* __restrict__ emb_b, float* __restrict__ fx)
{
    __shared__ float aT[32][68];
    __shared__ float wS[32][256];
    __shared__ float xs[128];
    int tid = threadIdx.x;
    int m0 = blockIdx.x * 64;
    int b = m0 / NN;
    if (tid < 128) xs[tid] = x[(size_t)m0*2 + tid];
    __syncthreads();
    float acc[4][16];
    #pragma unroll
    for (int a = 0; a < 4; ++a)
        #pragma unroll
        for (int c = 0; c < 16; ++c) acc[a][c] = 0.f;
    int tx = tid & 15, ty = tid >> 4;
    int lm = tid & 63, qq = tid >> 6;
    const float4* W4 = (const float4*)pre_w2;
    float4* wS4 = (float4*)&wS[0][0];
    float x0 = xs[lm*2], x1 = xs[lm*2 + 1];
    for (int kc = 0; kc < 512; kc += 32) {
        #pragma unroll
        for (int jj = 0; jj < 8; ++jj) {
            int kl = qq*8 + jj, k = kc + kl;
            aT[kl][lm] = gelu_f(x0*pre_w1[k] + x1*pre_w1[512 + k] + pre_b1[k]);
        }
        #pragma unroll
        for (int r = 0; r < 8; ++r) wS4[r*256 + tid] = W4[kc*64 + r*256 + tid];
        __syncthreads();
        #pragma unroll
        for (int k = 0; k < 32; ++k) {
            float4 av = *(const float4*)&aT[k][ty*4];
            #pragma unroll
            for (int ch = 0; ch < 4; ++ch) {
                float4 wv = *(const float4*)&wS[k][ch*64 + tx*4];
                acc[0][ch*4+0] += av.x*wv.x; acc[0][ch*4+1] += av.x*wv.y;
                acc[0][ch*4+2] += av.x*wv.z; acc[0][ch*4+3] += av.x*wv.w;
                acc[1][ch*4+0] += av.y*wv.x; acc[1][ch*4+1] += av.y*wv.y;
                acc[1][ch*4+2] += av.y*wv.z; acc[1][ch*4+3] += av.y*wv.w;
                acc[2][ch*4+0] += av.z*wv.x; acc[2][ch*4+1] += av.z*wv.y;
                acc[2][ch*4+2] += av.z*wv.z; acc[2][ch*4+3] += av.z*wv.w;
                acc[3][ch*4+0] += av.w*wv.x; acc[3][ch*4+1] += av.w*wv.y;
                acc[3][ch*4+2] += av.w*wv.z; acc[3][ch*4+3] += av.w*wv.w;
            }
        }
        __syncthreads();
    }
    float c0 = condition[b*3+0], c1 = condition[b*3+1], c2 = condition[b*3+2];
    #pragma unroll
    for (int ch = 0; ch < 4; ++ch) {
        int cbase = ch*64 + tx*4;
        float e[4];
        #pragma unroll
        for (int j = 0; j < 4; ++j) {
            int c = cbase + j;
            e[j] = pre_b2[c] + placeholder[c] + emb_b[c]
                 + c0*emb_w[c] + c1*emb_w[HID + c] + c2*emb_w[2*HID + c];
        }
        #pragma unroll
        for (int mi = 0; mi < 4; ++mi) {
            int m = m0 + ty*4 + mi;
            float4 o4 = make_float4(acc[mi][ch*4+0]+e[0], acc[mi][ch*4+1]+e[1],
                                    acc[mi][ch*4+2]+e[2], acc[mi][ch*4+3]+e[3]);
            *(float4*)&fx[(size_t)m*HID + cbase] = o4;
        }
    }
}

// ---------------------------------------------------------------------------
// Generic K=256 GEMM, tile 64x256, grid NT/64.
// mode 0: out = rstd*(acc - mu*u[c]) + cst[c]           (LN-folded, A1)
// mode 1: same + gelu                                    (C2)
// mode 2: out = acc + bias[c] + res[m][c]                (C1/C3 residual)
// ---------------------------------------------------------------------------
__global__ __launch_bounds__(256) void k_gemm(
    const float* __restrict__ A, const float* __restrict__ W,
    float* __restrict__ out,
    const float* __restrict__ mu, const float* __restrict__ rstd,
    const float* __restrict__ u, const float* __restrict__ cst,
    const float* __restrict__ bias, const float* __restrict__ res,
    int mode)
{
    __shared__ float aT[32][68];
    __shared__ float wS[32][256];
    int tid = threadIdx.x;
    int m0 = blockIdx.x * 64;
    int tx = tid & 15, ty = tid >> 4;
    int lm = tid >> 2, qc = (tid & 3) * 8;
    float acc[4][16];
    #pragma unroll
    for (int a = 0; a < 4; ++a)
        #pragma unroll
        for (int c = 0; c < 16; ++c) acc[a][c] = 0.f;
    const float4* W4 = (const float4*)W;
    float4* wS4 = (float4*)&wS[0][0];
    for (int kc = 0; kc < 256; kc += 32) {
        const float* ap = A + (size_t)(m0 + lm)*HID + kc + qc;
        float4 v0 = *(const float4*)ap;
        float4 v1 = *(const float4*)(ap + 4);
        aT[qc+0][lm] = v0.x; aT[qc+1][lm] = v0.y; aT[qc+2][lm] = v0.z; aT[qc+3][lm] = v0.w;
        aT[qc+4][lm] = v1.x; aT[qc+5][lm] = v1.y; aT[qc+6][lm] = v1.z; aT[qc+7][lm] = v1.w;
        #pragma unroll
        for (int r = 0; r < 8; ++r) wS4[r*256 + tid] = W4[kc*64 + r*256 + tid];
        __syncthreads();
        #pragma unroll
        for (int k = 0; k < 32; ++k) {
            float4 av = *(const float4*)&aT[k][ty*4];
            #pragma unroll
            for (int ch = 0; ch < 4; ++ch) {
                float4 wv = *(const float4*)&wS[k][ch*64 + tx*4];
                acc[0][ch*4+0] += av.x*wv.x; acc[0][ch*4+1] += av.x*wv.y;
                acc[0][ch*4+2] += av.x*wv.z; acc[0][ch*4+3] += av.x*wv.w;
                acc[1][ch*4+0] += av.y*wv.x; acc[1][ch*4+1] += av.y*wv.y;
                acc[1][ch*4+2] += av.y*wv.z; acc[1][ch*4+3] += av.y*wv.w;
                acc[2][ch*4+0] += av.z*wv.x; acc[2][ch*4+1] += av.z*wv.y;
                acc[2][ch*4+2] += av.z*wv.z; acc[2][ch*4+3] += av.z*wv.w;
                acc[3][ch*4+0] += av.w*wv.x; acc[3][ch*4+1] += av.w*wv.y;
                acc[3][ch*4+2] += av.w*wv.z; acc[3][ch*4+3] += av.w*wv.w;
            }
        }
        __syncthreads();
    }
    int mbase = m0 + ty*4;
    if (mode == 2) {
        #pragma unroll
        for (int ch = 0; ch < 4; ++ch) {
            int cbase = ch*64 + tx*4;
            float4 bv = *(const float4*)&bias[cbase];
            #pragma unroll
            for (int mi = 0; mi < 4; ++mi) {
                float4 rv = *(const float4*)&res[(size_t)(mbase + mi)*HID + cbase];
                float4 o4 = make_float4(acc[mi][ch*4+0] + bv.x + rv.x,
                                        acc[mi][ch*4+1] + bv.y + rv.y,
                                        acc[mi][ch*4+2] + bv.z + rv.z,
                                        acc[mi][ch*4+3] + bv.w + rv.w);
                *(float4*)&out[(size_t)(mbase + mi)*HID + cbase] = o4;
            }
        }
    } else {
        float mu_[4], rs_[4];
        #pragma unroll
        for (int mi = 0; mi < 4; ++mi) { mu_[mi] = mu[mbase+mi]; rs_[mi] = rstd[mbase+mi]; }
        #pragma unroll
        for (int ch = 0; ch < 4; ++ch) {
            int cbase = ch*64 + tx*4;
            float4 uv = *(const float4*)&u[cbase];
            float4 cv = *(const float4*)&cst[cbase];
            #pragma unroll
            for (int mi = 0; mi < 4; ++mi) {
                float4 o4;
                o4.x = rs_[mi]*(acc[mi][ch*4+0] - mu_[mi]*uv.x) + cv.x;
                o4.y = rs_[mi]*(acc[mi][ch*4+1] - mu_[mi]*uv.y) + cv.y;
                o4.z = rs_[mi]*(acc[mi][ch*4+2] - mu_[mi]*uv.z) + cv.z;
                o4.w = rs_[mi]*(acc[mi][ch*4+3] - mu_[mi]*uv.w) + cv.w;
                if (mode == 1) {
                    o4.x = gelu_f(o4.x); o4.y = gelu_f(o4.y);
                    o4.z = gelu_f(o4.z); o4.w = gelu_f(o4.w);
                }
                *(float4*)&out[(size_t)(mbase + mi)*HID + cbase] = o4;
            }
        }
    }
}

// ---------------------------------------------------------------------------
// A2: per-token temp + gumbel-softmax sw, accumulate st/norm.
// R1: 64 tokens/block (grid NT/64 = 1024 -> 4 blocks/CU, 16 waves/CU vs the
// R0 1-block/CU latency disaster), unroll-2 token loop for dual-chain ILP.
// thread = (h,g) pair; st rows in registers; block-amortized atomics.
// ---------------------------------------------------------------------------
__global__ __launch_bounds__(256) void k_a2(
    const float* __restrict__ xm, const float* __restrict__ gumbel,
    const float* __restrict__ pt_w1, const float* __restrict__ pt_b1,
    const float* __restrict__ pt_w2, const float* __restrict__ pt_b2,
    const float* __restrict__ ps_w, const float* __restrict__ ps_b,
    const float* __restrict__ attn_bias,
    float* __restrict__ sw, float* __restrict__ st, float* __restrict__ nrm,
    int layer)
{
    __shared__ float xm_l[16][256];
    __shared__ float ptw1_l[32][32];
    __shared__ float psw_l[32][32];
    __shared__ float ptb1_l[32], psb_l[32];
    int tid = threadIdx.x;
    int m0 = blockIdx.x * 64;
    int b = m0 / NN;
    int n0 = m0 % NN;
    int h = tid >> 5, g = tid & 31;
    #pragma unroll
    for (int r = 0; r < 4; ++r) {
        ((float*)ptw1_l)[r*256 + tid] = pt_w1[layer*DHH*GG + r*256 + tid];
        ((float*)psw_l)[r*256 + tid]  = ps_w [layer*DHH*GG + r*256 + tid];
    }
    if (tid < 32) { ptb1_l[tid] = pt_b1[layer*GG + tid]; psb_l[tid] = ps_b[layer*GG + tid]; }
    float ptw2_g = pt_w2[layer*GG + g];
    float ptb2   = pt_b2[layer];
    float ab     = attn_bias[layer*HH + h];
    float stacc[32];
    #pragma unroll
    for (int c = 0; c < 32; ++c) stacc[c] = 0.f;
    float nacc = 0.f;
    const float* gum = gumbel + (size_t)((layer*BB + b)*HH + h)*NN*GG;
    float* swp = sw + (size_t)(b*HH + h)*NN*GG;
    __syncthreads();
    for (int mc = 0; mc < 4; ++mc) {
        #pragma unroll
        for (int r = 0; r < 16; ++r)
            xm_l[r][tid] = xm[(size_t)(m0 + mc*16 + r)*HID + tid];
        __syncthreads();
        #pragma unroll 2
        for (int ml = 0; ml < 16; ++ml) {
            int n = n0 + mc*16 + ml;
            float xr[32];
            #pragma unroll
            for (int c4 = 0; c4 < 8; ++c4) {
                float4 v = *(const float4*)&xm_l[ml][h*32 + c4*4];
                xr[c4*4+0] = v.x; xr[c4*4+1] = v.y; xr[c4*4+2] = v.z; xr[c4*4+3] = v.w;
            }
            float t1 = ptb1_l[g];
            #pragma unroll
            for (int c = 0; c < 32; ++c) t1 += xr[c] * ptw1_l[c][g];
            t1 = gelu_f(t1);
            float s = t1 * ptw2_g;
            #pragma unroll
            for (int off = 16; off >= 1; off >>= 1) s += __shfl_xor(s, off);
            float temp = fmaxf(gelu_f(s + ptb2) + ab, 0.01f);
            float lg = psb_l[g];
            #pragma unroll
            for (int c = 0; c < 32; ++c) lg += xr[c] * psw_l[c][g];
            float gu = gum[(size_t)n*GG + g];
            float gn = -logf(-logf(gu + 1e-8f) + 1e-8f);
            lg = (lg + gn) / temp;
            float mx = lg;
            #pragma unroll
            for (int off = 16; off >= 1; off >>= 1) mx = fmaxf(mx, __shfl_xor(mx, off));
            float e = expf(lg - mx);
            float se = e;
            #pragma unroll
            for (int off = 16; off >= 1; off >>= 1) se += __shfl_xor(se, off);
            float swv = e / se;
            swp[(size_t)n*GG + g] = swv;
            nacc += swv;
            #pragma unroll
            for (int c = 0; c < 32; ++c) stacc[c] += swv * xr[c];
        }
        __syncthreads();
    }
    float* stp = st + (size_t)(b*HH + h)*GG*DHH + g*DHH;
    #pragma unroll
    for (int c = 0; c < 32; ++c) atomicAdd(&stp[c], stacc[c]);
    atomicAdd(&nrm[(b*HH + h)*GG + g], nacc);
}

// ---------------------------------------------------------------------------
// B: slice-token attention per (b,h). grid = B*H = 32 blocks.
// ---------------------------------------------------------------------------
__global__ __launch_bounds__(256) void k_b(
    const float* __restrict__ st, const float* __restrict__ nrm,
    const float* __restrict__ q_w, const float* __restrict__ k_w, const float* __restrict__ v_w,
    float* __restrict__ o, int layer)
{
    __shared__ float st_l[32][33], q_l[32][33], k_l[32][33], v_l[32][33], a_l[32][33];
    __shared__ float wq[32][32], wk[32][32], wv[32][32];
    int tid = threadIdx.x;
    int bh = blockIdx.x;
    #pragma unroll
    for (int r = 0; r < 4; ++r) {
        ((float*)wq)[r*256 + tid] = q_w[(size_t)layer*DHH*DHH + r*256 + tid];
        ((float*)wk)[r*256 + tid] = k_w[(size_t)layer*DHH*DHH + r*256 + tid];
        ((float*)wv)[r*256 + tid] = v_w[(size_t)layer*DHH*DHH + r*256 + tid];
    }
    #pragma unroll
    for (int r = 0; r < 4; ++r) {
        int idx = r*256 + tid;
        int gg2 = idx >> 5, cc = idx & 31;
        st_l[gg2][cc] = st[(size_t)bh*GG*DHH + idx] / (nrm[bh*GG + gg2] + 1e-5f);
    }
    __syncthreads();
    int g2 = tid >> 3, c4 = (tid & 7) * 4;
    float aq[4] = {0,0,0,0}, ak[4] = {0,0,0,0}, avv[4] = {0,0,0,0};
    #pragma unroll
    for (int k = 0; k < 32; ++k) {
        float sv = st_l[g2][k];
        #pragma unroll
        for (int j = 0; j < 4; ++j) {
            aq[j]  += sv * wq[k][c4+j];
            ak[j]  += sv * wk[k][c4+j];
            avv[j] += sv * wv[k][c4+j];
        }
    }
    #pragma unroll
    for (int j = 0; j < 4; ++j) { q_l[g2][c4+j] = aq[j]; k_l[g2][c4+j] = ak[j]; v_l[g2][c4+j] = avv[j]; }
    __syncthreads();
    if (tid < 32) {
        int gq = tid;
        float sc[32];
        float mx = -1e30f;
        #pragma unroll
        for (int j = 0; j < 32; ++j) {
            float s2 = 0.f;
            #pragma unroll
            for (int c = 0; c < 32; ++c) s2 += q_l[gq][c] * k_l[j][c];
            s2 *= 0.17677669529663687f;  // 1/sqrt(32)
            sc[j] = s2;
            mx = fmaxf(mx, s2);
        }
        float se = 0.f;
        #pragma unroll
        for (int j = 0; j < 32; ++j) { sc[j] = expf(sc[j] - mx); se += sc[j]; }
        float inv = 1.f / se;
        #pragma unroll
        for (int j = 0; j < 32; ++j) a_l[gq][j] = sc[j] * inv;
    }
    __syncthreads();
    float ao[4] = {0,0,0,0};
    #pragma unroll
    for (int k2 = 0; k2 < 32; ++k2) {
        float aw = a_l[g2][k2];
        #pragma unroll
        for (int j = 0; j < 4; ++j) ao[j] += aw * v_l[k2][c4+j];
    }
    #pragma unroll
    for (int j = 0; j < 4; ++j) o[(size_t)bh*GG*DHH + g2*DHH + c4 + j] = ao[j];
}

// ---------------------------------------------------------------------------
// ox scatter-back: ox[n, h*32+c] = sum_g o[b,h,g,c] * sw[b,h,n,g]. grid NT/64.
// ---------------------------------------------------------------------------
__global__ __launch_bounds__(256) void k_ox(
    const float* __restrict__ sw, const float* __restrict__ o, float* __restrict__ ox)
{
    __shared__ float o_l[8192];
    __shared__ float sw_l[16][256];
    int tid = threadIdx.x;
    int m0 = blockIdx.x * 64;
    int b = m0 / NN;
    int n0 = m0 % NN;
    int h = tid >> 5, c = tid & 31;
    #pragma unroll
    for (int r = 0; r < 32; ++r) o_l[r*256 + tid] = o[(size_t)b*HH*GG*DHH + r*256 + tid];
    __syncthreads();
    for (int mc = 0; mc < 4; ++mc) {
        #pragma unroll
        for (int r = 0; r < 16; ++r)
            sw_l[r][tid] = sw[(size_t)((b*HH + h)*NN + n0 + mc*16 + r)*GG + c];
        __syncthreads();
        for (int ml = 0; ml < 16; ++ml) {
            float acc2 = 0.f;
            #pragma unroll
            for (int gg2 = 0; gg2 < 32; ++gg2)
                acc2 += sw_l[ml][h*32 + gg2] * o_l[(h*32 + gg2)*32 + c];
            ox[(size_t)(m0 + mc*16 + ml)*HID + tid] = acc2;
        }
        __syncthreads();
    }
}

// ---------------------------------------------------------------------------
// Head: out = LN3(fx) @ head_w + head_b. grid NT/64.
// ---------------------------------------------------------------------------
__global__ __launch_bounds__(256) void k_head(
    const float* __restrict__ fx, const float* __restrict__ mu, const float* __restrict__ rstd,
    const float* __restrict__ g3, const float* __restrict__ b3,
    const float* __restrict__ hw, const float* __restrict__ hb,
    float* __restrict__ out)
{
    __shared__ float fx_l[64][257];
    int tid = threadIdx.x;
    int m0 = blockIdx.x * 64;
    for (int r = 0; r < 64; ++r) fx_l[r][tid] = fx[(size_t)(m0 + r)*HID + tid];
    __syncthreads();
    int ml = tid & 63, oo = tid >> 6;
    float mu_ = mu[m0 + ml], rs_ = rstd[m0 + ml];
    float acc2 = hb[oo];
    #pragma unroll 8
    for (int k = 0; k < HID; ++k) {
        float hv = (fx_l[ml][k] - mu_) * rs_ * g3[k] + b3[k];
        acc2 += hv * hw[k*4 + oo];
    }
    out[(size_t)(m0 + ml)*4 + oo] = acc2;
}

// ---------------------------------------------------------------------------
extern "C" void kernel_launch(void* const* d_in, const int* in_sizes, int n_in,
                              void* d_out, int out_size, void* d_ws, size_t ws_size,
                              hipStream_t stream)
{
    (void)in_sizes; (void)n_in; (void)out_size; (void)ws_size;
    const float* x          = (const float*)d_in[0];
    const float* condition  = (const float*)d_in[1];
    const float* gumbel     = (const float*)d_in[2];
    const float* pre_w1     = (const float*)d_in[3];
    const float* pre_b1     = (const float*)d_in[4];
    const float* pre_w2     = (const float*)d_in[5];
    const float* pre_b2     = (const float*)d_in[6];
    const float* placeholder= (const float*)d_in[7];
    const float* emb_w      = (const float*)d_in[8];
    const float* emb_b      = (const float*)d_in[9];
    const float* ln1_g      = (const float*)d_in[10];
    const float* ln1_b      = (const float*)d_in[11];
    const float* attn_bias  = (const float*)d_in[12];
    const float* pt_w1      = (const float*)d_in[13];
    const float* pt_b1      = (const float*)d_in[14];
    const float* pt_w2      = (const float*)d_in[15];
    const float* pt_b2      = (const float*)d_in[16];
    const float* px_w       = (const float*)d_in[17];
    const float* px_b       = (const float*)d_in[18];
    const float* ps_w       = (const float*)d_in[19];
    const float* ps_b       = (const float*)d_in[20];
    const float* q_w        = (const float*)d_in[21];
    const float* k_w        = (const float*)d_in[22];
    const float* v_w        = (const float*)d_in[23];
    const float* o_w        = (const float*)d_in[24];
    const float* o_b        = (const float*)d_in[25];
    const float* ln2_g      = (const float*)d_in[26];
    const float* ln2_b      = (const float*)d_in[27];
    const float* mlp_w1     = (const float*)d_in[28];
    const float* mlp_b1     = (const float*)d_in[29];
    const float* mlp_w2     = (const float*)d_in[30];
    const float* mlp_b2     = (const float*)d_in[31];
    const float* ln3_g      = (const float*)d_in[32];
    const float* ln3_b      = (const float*)d_in[33];
    const float* head_w     = (const float*)d_in[34];
    const float* head_b     = (const float*)d_in[35];

    float* ws   = (float*)d_ws;
    float* fx   = ws;                                   // NT*HID
    float* scr  = fx  + (size_t)NT*HID;                 // NT*HID (xm / ox / t)
    float* sw   = scr + (size_t)NT*HID;                 // B*H*N*G
    float* mu   = sw  + (size_t)BB*HH*NN*GG;            // NT
    float* rstd = mu  + NT;                             // NT
    float* st   = rstd+ NT;                             // B*H*G*DH = 32768
    float* nrm  = st  + BB*HH*GG*DHH;                   // 1024
    float* o    = nrm + BB*HH*GG;                       // 32768
    float* wp   = o   + BB*HH*GG*DHH;                   // 10*WSEG

    dim3 blk(256);
    k_wprep<<<2*LL, blk, 0, stream>>>(px_w, px_b, ln1_g, ln1_b, mlp_w1, mlp_b1, ln2_g, ln2_b, wp);
    k_pre<<<NT/64, blk, 0, stream>>>(x, condition, pre_w1, pre_b1, pre_w2, pre_b2,
                                     placeholder, emb_w, emb_b, fx);
    for (int i = 0; i < LL; ++i) {
        float* wpx = wp + (size_t)(i*2 + 0)*WSEG;
        float* wm1 = wp + (size_t)(i*2 + 1)*WSEG;
        k_stats<<<NT/64, blk, 0, stream>>>(fx, mu, rstd);
        k_zero<<<(33792 + 255)/256, blk, 0, stream>>>(st, 33792);
        k_gemm<<<NT/64, blk, 0, stream>>>(fx, wpx, scr, mu, rstd,
                                          wpx + HID*HID, wpx + HID*HID + HID,
                                          nullptr, nullptr, 0);
        k_a2<<<NT/64, blk, 0, stream>>>(scr, gumbel, pt_w1, pt_b1, pt_w2, pt_b2,
                                        ps_w, ps_b, attn_bias, sw, st, nrm, i);
        k_b<<<BB*HH, blk, 0, stream>>>(st, nrm, q_w, k_w, v_w, o, i);
        k_ox<<<NT/64, blk, 0, stream>>>(sw, o, scr);
        k_gemm<<<NT/64, blk, 0, stream>>>(scr, o_w + (size_t)i*HID*HID, fx,
                                          nullptr, nullptr, nullptr, nullptr,
                                          o_b + i*HID, fx, 2);
        k_stats<<<NT/64, blk, 0, stream>>>(fx, mu, rstd);
        k_gemm<<<NT/64, blk, 0, stream>>>(fx, wm1, scr, mu, rstd,
                                          wm1 + HID*HID, wm1 + HID*HID + HID,
                                          nullptr, nullptr, 1);
        k_gemm<<<NT/64, blk, 0, stream>>>(scr, mlp_w2 + (size_t)i*HID*HID, fx,
                                          nullptr, nullptr, nullptr, nullptr,
                                          mlp_b2 + i*HID, fx, 2);
    }
    k_stats<<<NT/64, blk, 0, stream>>>(fx, mu, rstd);
    k_head<<<NT/64, blk, 0, stream>>>(fx, mu, rstd, ln3_g, ln3_b, head_w, head_b, (float*)d_out);
}

// Round 3
// 6095.877 us; speedup vs baseline: 1.0063x; 1.0063x over previous
//
#include <hip/hip_runtime.h>
#include <math.h>

constexpr int LL  = 5;
constexpr int BB  = 4;
constexpr int NN  = 16384;
constexpr int HH  = 8;
constexpr int DHH = 32;
constexpr int GG  = 32;
constexpr int HID = 256;
constexpr int NT  = BB * NN;           // 65536 tokens
constexpr int WSEG = HID * HID + 2 * HID;  // 66048 floats per prepped matrix

__device__ __forceinline__ float gelu_f(float x) {
    return x * 0.5f * (1.0f + erff(x * 0.70710678118654752f));
}

// ---------------------------------------------------------------------------
// Prep: W' = g[k]*W[k,c]; u[c] = sum_k g[k]W[k,c]; cst[c] = sum_k b[k]W[k,c] + bias[c]
// grid = 10 blocks (layer*2 + {px, mlp1}), 256 threads
// ---------------------------------------------------------------------------
__global__ __launch_bounds__(256) void k_wprep(
    const float* __restrict__ px_w, const float* __restrict__ px_b,
    const float* __restrict__ ln1_g, const float* __restrict__ ln1_b,
    const float* __restrict__ mlp_w1, const float* __restrict__ mlp_b1,
    const float* __restrict__ ln2_g, const float* __restrict__ ln2_b,
    float* __restrict__ wp)
{
    int bid = blockIdx.x;
    int i = bid >> 1, which = bid & 1;
    const float *W, *g, *bln, *bias;
    if (which == 0) { W = px_w  + (size_t)i*HID*HID; g = ln1_g + i*HID; bln = ln1_b + i*HID; bias = px_b  + i*HID; }
    else            { W = mlp_w1+ (size_t)i*HID*HID; g = ln2_g + i*HID; bln = ln2_b + i*HID; bias = mlp_b1+ i*HID; }
    float* dst = wp + (size_t)bid * WSEG;
    float* u   = dst + HID*HID;
    float* cst = u + HID;
    int c = threadIdx.x;
    float au = 0.f, ac = 0.f;
    #pragma unroll 8
    for (int k = 0; k < HID; ++k) {
        float w  = W[k*HID + c];
        float gw = g[k] * w;
        dst[k*HID + c] = gw;
        au += gw;
        ac += bln[k] * w;
    }
    u[c] = au;
    cst[c] = ac + bias[c];
}

// ---------------------------------------------------------------------------
// Row stats (mean, rstd) over HID=256 for all NT tokens. grid = NT/64.
// ---------------------------------------------------------------------------
__global__ __launch_bounds__(256) void k_stats(
    const float* __restrict__ src, float* __restrict__ mu, float* __restrict__ rstd)
{
    int m0 = blockIdx.x * 64;
    int tid = threadIdx.x;
    int ml = tid >> 4, q = tid & 15;
    for (int it = 0; it < 4; ++it) {
        int m = m0 + it*16 + ml;
        const float* p = src + (size_t)m*HID + q*16;
        float s = 0.f, ss = 0.f;
        #pragma unroll
        for (int j = 0; j < 4; ++j) {
            float4 v = *(const float4*)(p + j*4);
            s  += v.x + v.y + v.z + v.w;
            ss += v.x*v.x + v.y*v.y + v.z*v.z + v.w*v.w;
        }
        #pragma unroll
        for (int off = 8; off >= 1; off >>= 1) {
            s  += __shfl_xor(s, off);
            ss += __shfl_xor(ss, off);
        }
        if (q == 0) {
            float mm = s * (1.f/HID);
            float vv = ss * (1.f/HID) - mm*mm;
            mu[m] = mm;
            rstd[m] = rsqrtf(vv + 1e-5f);
        }
    }
}

__global__ __launch_bounds__(256) void k_zero(float* __restrict__ p, int n)
{
    int i = blockIdx.x * 256 + threadIdx.x;
    if (i < n) p[i] = 0.f;
}

// ---------------------------------------------------------------------------
// Preprocess MLP: fx = gelu(x@pre_w1+b1)@pre_w2 + b2 + placeholder + cond_emb
// K = 512, tile 64 tokens x 256 channels. grid = NT/64.
// ---------------------------------------------------------------------------
__global__ __launch_bounds__(256) void k_pre(
    const float* __restrict__ x, const float* __restrict__ condition,
    const float* __restrict__ pre_w1, const float* __restrict__ pre_b1,
    const float* __restrict__ pre_w2, const float* __restrict__ pre_b2,
    const float* __restrict__ placeholder, const float* __restrict__ emb_w,
    const float* __restrict__ emb_b, float* __restrict__ fx)
{
    __shared__ float aT[32][68];
    __shared__ float wS[32][256];
    __shared__ float xs[128];
    int tid = threadIdx.x;
    int m0 = blockIdx.x * 64;
    int b = m0 / NN;
    if (tid < 128) xs[tid] = x[(size_t)m0*2 + tid];
    __syncthreads();
    float acc[4][16];
    #pragma unroll
    for (int a = 0; a < 4; ++a)
        #pragma unroll
        for (int c = 0; c < 16; ++c) acc[a][c] = 0.f;
    int tx = tid & 15, ty = tid >> 4;
    int lm = tid & 63, qq = tid >> 6;
    const float4* W4 = (const float4*)pre_w2;
    float4* wS4 = (float4*)&wS[0][0];
    float x0 = xs[lm*2], x1 = xs[lm*2 + 1];
    for (int kc = 0; kc < 512; kc += 32) {
        #pragma unroll
        for (int jj = 0; jj < 8; ++jj) {
            int kl = qq*8 + jj, k = kc + kl;
            aT[kl][lm] = gelu_f(x0*pre_w1[k] + x1*pre_w1[512 + k] + pre_b1[k]);
        }
        #pragma unroll
        for (int r = 0; r < 8; ++r) wS4[r*256 + tid] = W4[kc*64 + r*256 + tid];
        __syncthreads();
        #pragma unroll
        for (int k = 0; k < 32; ++k) {
            float4 av = *(const float4*)&aT[k][ty*4];
            #pragma unroll
            for (int ch = 0; ch < 4; ++ch) {
                float4 wv = *(const float4*)&wS[k][ch*64 + tx*4];
                acc[0][ch*4+0] += av.x*wv.x; acc[0][ch*4+1] += av.x*wv.y;
                acc[0][ch*4+2] += av.x*wv.z; acc[0][ch*4+3] += av.x*wv.w;
                acc[1][ch*4+0] += av.y*wv.x; acc[1][ch*4+1] += av.y*wv.y;
                acc[1][ch*4+2] += av.y*wv.z; acc[1][ch*4+3] += av.y*wv.w;
                acc[2][ch*4+0] += av.z*wv.x; acc[2][ch*4+1] += av.z*wv.y;
                acc[2][ch*4+2] += av.z*wv.z; acc[2][ch*4+3] += av.z*wv.w;
                acc[3][ch*4+0] += av.w*wv.x; acc[3][ch*4+1] += av.w*wv.y;
                acc[3][ch*4+2] += av.w*wv.z; acc[3][ch*4+3] += av.w*wv.w;
            }
        }
        __syncthreads();
    }
    float c0 = condition[b*3+0], c1 = condition[b*3+1], c2 = condition[b*3+2];
    #pragma unroll
    for (int ch = 0; ch < 4; ++ch) {
        int cbase = ch*64 + tx*4;
        float e[4];
        #pragma unroll
        for (int j = 0; j < 4; ++j) {
            int c = cbase + j;
            e[j] = pre_b2[c] + placeholder[c] + emb_b[c]
                 + c0*emb_w[c] + c1*emb_w[HID + c] + c2*emb_w[2*HID + c];
        }
        #pragma unroll
        for (int mi = 0; mi < 4; ++mi) {
            int m = m0 + ty*4 + mi;
            float4 o4 = make_float4(acc[mi][ch*4+0]+e[0], acc[mi][ch*4+1]+e[1],
                                    acc[mi][ch*4+2]+e[2], acc[mi][ch*4+3]+e[3]);
            *(float4*)&fx[(size_t)m*HID + cbase] = o4;
        }
    }
}

// ---------------------------------------------------------------------------
// Generic K=256 GEMM, tile 64x256, grid NT/64.
// mode 0: out = rstd*(acc - mu*u[c]) + cst[c]           (LN-folded, A1)
// mode 1: same + gelu                                    (C2)
// mode 2: out = acc + bias[c] + res[m][c]                (C1/C3 residual)
// ---------------------------------------------------------------------------
__global__ __launch_bounds__(256) void k_gemm(
    const float* __restrict__ A, const float* __restrict__ W,
    float* __restrict__ out,
    const float* __restrict__ mu, const float* __restrict__ rstd,
    const float* __restrict__ u, const float* __restrict__ cst,
    const float* __restrict__ bias, const float* __restrict__ res,
    int mode)
{
    __shared__ float aT[32][68];
    __shared__ float wS[32][256];
    int tid = threadIdx.x;
    int m0 = blockIdx.x * 64;
    int tx = tid & 15, ty = tid >> 4;
    int lm = tid >> 2, qc = (tid & 3) * 8;
    float acc[4][16];
    #pragma unroll
    for (int a = 0; a < 4; ++a)
        #pragma unroll
        for (int c = 0; c < 16; ++c) acc[a][c] = 0.f;
    const float4* W4 = (const float4*)W;
    float4* wS4 = (float4*)&wS[0][0];
    for (int kc = 0; kc < 256; kc += 32) {
        const float* ap = A + (size_t)(m0 + lm)*HID + kc + qc;
        float4 v0 = *(const float4*)ap;
        float4 v1 = *(const float4*)(ap + 4);
        aT[qc+0][lm] = v0.x; aT[qc+1][lm] = v0.y; aT[qc+2][lm] = v0.z; aT[qc+3][lm] = v0.w;
        aT[qc+4][lm] = v1.x; aT[qc+5][lm] = v1.y; aT[qc+6][lm] = v1.z; aT[qc+7][lm] = v1.w;
        #pragma unroll
        for (int r = 0; r < 8; ++r) wS4[r*256 + tid] = W4[kc*64 + r*256 + tid];
        __syncthreads();
        #pragma unroll
        for (int k = 0; k < 32; ++k) {
            float4 av = *(const float4*)&aT[k][ty*4];
            #pragma unroll
            for (int ch = 0; ch < 4; ++ch) {
                float4 wv = *(const float4*)&wS[k][ch*64 + tx*4];
                acc[0][ch*4+0] += av.x*wv.x; acc[0][ch*4+1] += av.x*wv.y;
                acc[0][ch*4+2] += av.x*wv.z; acc[0][ch*4+3] += av.x*wv.w;
                acc[1][ch*4+0] += av.y*wv.x; acc[1][ch*4+1] += av.y*wv.y;
                acc[1][ch*4+2] += av.y*wv.z; acc[1][ch*4+3] += av.y*wv.w;
                acc[2][ch*4+0] += av.z*wv.x; acc[2][ch*4+1] += av.z*wv.y;
                acc[2][ch*4+2] += av.z*wv.z; acc[2][ch*4+3] += av.z*wv.w;
                acc[3][ch*4+0] += av.w*wv.x; acc[3][ch*4+1] += av.w*wv.y;
                acc[3][ch*4+2] += av.w*wv.z; acc[3][ch*4+3] += av.w*wv.w;
            }
        }
        __syncthreads();
    }
    int mbase = m0 + ty*4;
    if (mode == 2) {
        #pragma unroll
        for (int ch = 0; ch < 4; ++ch) {
            int cbase = ch*64 + tx*4;
            float4 bv = *(const float4*)&bias[cbase];
            #pragma unroll
            for (int mi = 0; mi < 4; ++mi) {
                float4 rv = *(const float4*)&res[(size_t)(mbase + mi)*HID + cbase];
                float4 o4 = make_float4(acc[mi][ch*4+0] + bv.x + rv.x,
                                        acc[mi][ch*4+1] + bv.y + rv.y,
                                        acc[mi][ch*4+2] + bv.z + rv.z,
                                        acc[mi][ch*4+3] + bv.w + rv.w);
                *(float4*)&out[(size_t)(mbase + mi)*HID + cbase] = o4;
            }
        }
    } else {
        float mu_[4], rs_[4];
        #pragma unroll
        for (int mi = 0; mi < 4; ++mi) { mu_[mi] = mu[mbase+mi]; rs_[mi] = rstd[mbase+mi]; }
        #pragma unroll
        for (int ch = 0; ch < 4; ++ch) {
            int cbase = ch*64 + tx*4;
            float4 uv = *(const float4*)&u[cbase];
            float4 cv = *(const float4*)&cst[cbase];
            #pragma unroll
            for (int mi = 0; mi < 4; ++mi) {
                float4 o4;
                o4.x = rs_[mi]*(acc[mi][ch*4+0] - mu_[mi]*uv.x) + cv.x;
                o4.y = rs_[mi]*(acc[mi][ch*4+1] - mu_[mi]*uv.y) + cv.y;
                o4.z = rs_[mi]*(acc[mi][ch*4+2] - mu_[mi]*uv.z) + cv.z;
                o4.w = rs_[mi]*(acc[mi][ch*4+3] - mu_[mi]*uv.w) + cv.w;
                if (mode == 1) {
                    o4.x = gelu_f(o4.x); o4.y = gelu_f(o4.y);
                    o4.z = gelu_f(o4.z); o4.w = gelu_f(o4.w);
                }
                *(float4*)&out[(size_t)(mbase + mi)*HID + cbase] = o4;
            }
        }
    }
}

// ---------------------------------------------------------------------------
// k_sw (R2): thread-per-(token,head). No shuffles, no LDS, no atomics.
// Weights indexed wave-uniformly -> s_load through scalar cache; each FMA is
// v_fma(v, s, v). Per-lane xm/gumbel/sw accesses are 128B-contiguous lines.
// grid = 32 bh * 64 = 2048 blocks, 256 tokens per block (one (b,h) each).
// ---------------------------------------------------------------------------
__global__ __launch_bounds__(256) void k_sw(
    const float* __restrict__ xm, const float* __restrict__ gumbel,
    const float* __restrict__ pt_w1, const float* __restrict__ pt_b1,
    const float* __restrict__ pt_w2, const float* __restrict__ pt_b2,
    const float* __restrict__ ps_w, const float* __restrict__ ps_b,
    const float* __restrict__ attn_bias, float* __restrict__ sw, int layer)
{
    int tid = threadIdx.x;
    int bh = blockIdx.x >> 6;
    int b = bh >> 3, h = bh & 7;
    int n = ((blockIdx.x & 63) << 8) + tid;
    const float* PT = pt_w1 + layer*DHH*GG;
    const float* PS = ps_w  + layer*DHH*GG;
    const float* B1 = pt_b1 + layer*GG;
    const float* BS = ps_b  + layer*GG;
    const float* W2 = pt_w2 + layer*GG;
    float ab   = attn_bias[layer*HH + h];
    float ptb2 = pt_b2[layer];

    float xr[32];
    const float4* xp = (const float4*)(xm + (size_t)(b*NN + n)*HID + h*DHH);
    #pragma unroll
    for (int j = 0; j < 8; ++j) {
        float4 v = xp[j];
        xr[4*j] = v.x; xr[4*j+1] = v.y; xr[4*j+2] = v.z; xr[4*j+3] = v.w;
    }
    float t1[32], lgv[32];
    #pragma unroll
    for (int g = 0; g < 32; ++g) { t1[g] = B1[g]; lgv[g] = BS[g]; }
    #pragma unroll
    for (int c = 0; c < 32; ++c) {
        float xc = xr[c];
        #pragma unroll
        for (int g = 0; g < 32; ++g) {
            t1[g]  += xc * PT[c*32 + g];
            lgv[g] += xc * PS[c*32 + g];
        }
    }
    float s = ptb2;
    #pragma unroll
    for (int g = 0; g < 32; ++g) s += gelu_f(t1[g]) * W2[g];
    float rt = 1.f / fmaxf(gelu_f(s) + ab, 0.01f);

    const float4* gp = (const float4*)(gumbel + ((size_t)((layer*BB + b)*HH + h)*NN + n)*GG);
    float mx = -1e30f;
    #pragma unroll
    for (int j = 0; j < 8; ++j) {
        float4 gv = gp[j];
        float g0 = -__logf(-__logf(gv.x + 1e-8f) + 1e-8f);
        float g1 = -__logf(-__logf(gv.y + 1e-8f) + 1e-8f);
        float g2 = -__logf(-__logf(gv.z + 1e-8f) + 1e-8f);
        float g3 = -__logf(-__logf(gv.w + 1e-8f) + 1e-8f);
        lgv[4*j+0] = (lgv[4*j+0] + g0) * rt;
        lgv[4*j+1] = (lgv[4*j+1] + g1) * rt;
        lgv[4*j+2] = (lgv[4*j+2] + g2) * rt;
        lgv[4*j+3] = (lgv[4*j+3] + g3) * rt;
        mx = fmaxf(mx, fmaxf(fmaxf(lgv[4*j+0], lgv[4*j+1]), fmaxf(lgv[4*j+2], lgv[4*j+3])));
    }
    float se = 0.f;
    #pragma unroll
    for (int g = 0; g < 32; ++g) { float e = __expf(lgv[g] - mx); lgv[g] = e; se += e; }
    float inv = 1.f / se;
    float4* op = (float4*)(sw + ((size_t)bh*NN + n)*GG);
    #pragma unroll
    for (int j = 0; j < 8; ++j)
        op[j] = make_float4(lgv[4*j]*inv, lgv[4*j+1]*inv, lgv[4*j+2]*inv, lgv[4*j+3]*inv);
}

// ---------------------------------------------------------------------------
// k_st (R2): st[bh][g][c] = sum_n sw[bh][n][g]*xm[b][n][h*32+c]; nrm = sum sw.
// 32x32 outer-product GEMM per (b,h): 512 blocks (32 bh x 16 chunks of 1024
// tokens). Each wave owns the full 32x32 tile as a 4x4 register tile per lane
// (2 ds_read_b128 -> 16 FMA), 8 tokens/tile/wave; LDS merge; spread atomics.
// ---------------------------------------------------------------------------
__global__ __launch_bounds__(256) void k_st(
    const float* __restrict__ sw, const float* __restrict__ xm,
    float* __restrict__ st, float* __restrict__ nrm)
{
    __shared__ float sw_l[1024];
    __shared__ float xm_l[1024];
    __shared__ float part[4096];
    int tid = threadIdx.x;
    int bh = blockIdx.x >> 4;
    int b = bh >> 3, h = bh & 7;
    int n0 = (blockIdx.x & 15) << 10;
    int w = tid >> 6, lane = tid & 63;
    int g0 = (lane & 7) * 4, c0 = (lane >> 3) * 4;
    int row = tid >> 3, col4 = (tid & 7) * 4;
    float acc[4][4];
    #pragma unroll
    for (int i = 0; i < 4; ++i)
        #pragma unroll
        for (int j = 0; j < 4; ++j) acc[i][j] = 0.f;
    float nacc[4] = {0.f, 0.f, 0.f, 0.f};

    for (int t8 = 0; t8 < 32; ++t8) {
        int nb = n0 + t8*32;
        *(float4*)&sw_l[tid*4] = ((const float4*)(sw + ((size_t)bh*NN + nb)*GG))[tid];
        *(float4*)&xm_l[tid*4] = *(const float4*)(xm + (size_t)(b*NN + nb + row)*HID + h*DHH + col4);
        __syncthreads();
        #pragma unroll
        for (int tt = 0; tt < 8; ++tt) {
            int t = w*8 + tt;
            float4 a  = *(float4*)&sw_l[t*32 + g0];
            float4 xv = *(float4*)&xm_l[t*32 + c0];
            acc[0][0] += a.x*xv.x; acc[0][1] += a.x*xv.y; acc[0][2] += a.x*xv.z; acc[0][3] += a.x*xv.w;
            acc[1][0] += a.y*xv.x; acc[1][1] += a.y*xv.y; acc[1][2] += a.y*xv.z; acc[1][3] += a.y*xv.w;
            acc[2][0] += a.z*xv.x; acc[2][1] += a.z*xv.y; acc[2][2] += a.z*xv.z; acc[2][3] += a.z*xv.w;
            acc[3][0] += a.w*xv.x; acc[3][1] += a.w*xv.y; acc[3][2] += a.w*xv.z; acc[3][3] += a.w*xv.w;
            nacc[0] += a.x; nacc[1] += a.y; nacc[2] += a.z; nacc[3] += a.w;
        }
        __syncthreads();
    }
    #pragma unroll
    for (int i = 0; i < 4; ++i)
        *(float4*)&part[w*1024 + (g0+i)*32 + c0] =
            make_float4(acc[i][0], acc[i][1], acc[i][2], acc[i][3]);
    __syncthreads();
    #pragma unroll
    for (int r = 0; r < 4; ++r) {
        int idx = r*256 + tid;
        float v = part[idx] + part[1024+idx] + part[2048+idx] + part[3072+idx];
        atomicAdd(&st[(size_t)bh*GG*DHH + idx], v);
    }
    if ((lane >> 3) == 0) {
        #pragma unroll
        for (int i = 0; i < 4; ++i)
            atomicAdd(&nrm[bh*GG + g0 + i], nacc[i]);
    }
}

// ---------------------------------------------------------------------------
// B: slice-token attention per (b,h). grid = B*H = 32 blocks.
// ---------------------------------------------------------------------------
__global__ __launch_bounds__(256) void k_b(
    const float* __restrict__ st, const float* __restrict__ nrm,
    const float* __restrict__ q_w, const float* __restrict__ k_w, const float* __restrict__ v_w,
    float* __restrict__ o, int layer)
{
    __shared__ float st_l[32][33], q_l[32][33], k_l[32][33], v_l[32][33], a_l[32][33];
    __shared__ float wq[32][32], wk[32][32], wv[32][32];
    int tid = threadIdx.x;
    int bh = blockIdx.x;
    #pragma unroll
    for (int r = 0; r < 4; ++r) {
        ((float*)wq)[r*256 + tid] = q_w[(size_t)layer*DHH*DHH + r*256 + tid];
        ((float*)wk)[r*256 + tid] = k_w[(size_t)layer*DHH*DHH + r*256 + tid];
        ((float*)wv)[r*256 + tid] = v_w[(size_t)layer*DHH*DHH + r*256 + tid];
    }
    #pragma unroll
    for (int r = 0; r < 4; ++r) {
        int idx = r*256 + tid;
        int gg2 = idx >> 5, cc = idx & 31;
        st_l[gg2][cc] = st[(size_t)bh*GG*DHH + idx] / (nrm[bh*GG + gg2] + 1e-5f);
    }
    __syncthreads();
    int g2 = tid >> 3, c4 = (tid & 7) * 4;
    float aq[4] = {0,0,0,0}, ak[4] = {0,0,0,0}, avv[4] = {0,0,0,0};
    #pragma unroll
    for (int k = 0; k < 32; ++k) {
        float sv = st_l[g2][k];
        #pragma unroll
        for (int j = 0; j < 4; ++j) {
            aq[j]  += sv * wq[k][c4+j];
            ak[j]  += sv * wk[k][c4+j];
            avv[j] += sv * wv[k][c4+j];
        }
    }
    #pragma unroll
    for (int j = 0; j < 4; ++j) { q_l[g2][c4+j] = aq[j]; k_l[g2][c4+j] = ak[j]; v_l[g2][c4+j] = avv[j]; }
    __syncthreads();
    if (tid < 32) {
        int gq = tid;
        float sc[32];
        float mx = -1e30f;
        #pragma unroll
        for (int j = 0; j < 32; ++j) {
            float s2 = 0.f;
            #pragma unroll
            for (int c = 0; c < 32; ++c) s2 += q_l[gq][c] * k_l[j][c];
            s2 *= 0.17677669529663687f;  // 1/sqrt(32)
            sc[j] = s2;
            mx = fmaxf(mx, s2);
        }
        float se = 0.f;
        #pragma unroll
        for (int j = 0; j < 32; ++j) { sc[j] = __expf(sc[j] - mx); se += sc[j]; }
        float inv = 1.f / se;
        #pragma unroll
        for (int j = 0; j < 32; ++j) a_l[gq][j] = sc[j] * inv;
    }
    __syncthreads();
    float ao[4] = {0,0,0,0};
    #pragma unroll
    for (int k2 = 0; k2 < 32; ++k2) {
        float aw = a_l[g2][k2];
        #pragma unroll
        for (int j = 0; j < 4; ++j) ao[j] += aw * v_l[k2][c4+j];
    }
    #pragma unroll
    for (int j = 0; j < 4; ++j) o[(size_t)bh*GG*DHH + g2*DHH + c4 + j] = ao[j];
}

// ---------------------------------------------------------------------------
// ox scatter-back: ox[n, h*32+c] = sum_g o[b,h,g,c] * sw[b,h,n,g]. grid NT/64.
// ---------------------------------------------------------------------------
__global__ __launch_bounds__(256) void k_ox(
    const float* __restrict__ sw, const float* __restrict__ o, float* __restrict__ ox)
{
    __shared__ float o_l[8192];
    __shared__ float sw_l[16][256];
    int tid = threadIdx.x;
    int m0 = blockIdx.x * 64;
    int b = m0 / NN;
    int n0 = m0 % NN;
    int h = tid >> 5, c = tid & 31;
    #pragma unroll
    for (int r = 0; r < 32; ++r) o_l[r*256 + tid] = o[(size_t)b*HH*GG*DHH + r*256 + tid];
    __syncthreads();
    for (int mc = 0; mc < 4; ++mc) {
        #pragma unroll
        for (int r = 0; r < 16; ++r)
            sw_l[r][tid] = sw[(size_t)((b*HH + h)*NN + n0 + mc*16 + r)*GG + c];
        __syncthreads();
        for (int ml = 0; ml < 16; ++ml) {
            float acc2 = 0.f;
            #pragma unroll
            for (int gg2 = 0; gg2 < 32; ++gg2)
                acc2 += sw_l[ml][h*32 + gg2] * o_l[(h*32 + gg2)*32 + c];
            ox[(size_t)(m0 + mc*16 + ml)*HID + tid] = acc2;
        }
        __syncthreads();
    }
}

// ---------------------------------------------------------------------------
// Head: out = LN3(fx) @ head_w + head_b. grid NT/64.
// ---------------------------------------------------------------------------
__global__ __launch_bounds__(256) void k_head(
    const float* __restrict__ fx, const float* __restrict__ mu, const float* __restrict__ rstd,
    const float* __restrict__ g3, const float* __restrict__ b3,
    const float* __restrict__ hw, const float* __restrict__ hb,
    float* __restrict__ out)
{
    __shared__ float fx_l[64][257];
    int tid = threadIdx.x;
    int m0 = blockIdx.x * 64;
    for (int r = 0; r < 64; ++r) fx_l[r][tid] = fx[(size_t)(m0 + r)*HID + tid];
    __syncthreads();
    int ml = tid & 63, oo = tid >> 6;
    float mu_ = mu[m0 + ml], rs_ = rstd[m0 + ml];
    float acc2 = hb[oo];
    #pragma unroll 8
    for (int k = 0; k < HID; ++k) {
        float hv = (fx_l[ml][k] - mu_) * rs_ * g3[k] + b3[k];
        acc2 += hv * hw[k*4 + oo];
    }
    out[(size_t)(m0 + ml)*4 + oo] = acc2;
}

// ---------------------------------------------------------------------------
extern "C" void kernel_launch(void* const* d_in, const int* in_sizes, int n_in,
                              void* d_out, int out_size, void* d_ws, size_t ws_size,
                              hipStream_t stream)
{
    (void)in_sizes; (void)n_in; (void)out_size; (void)ws_size;
    const float* x          = (const float*)d_in[0];
    const float* condition  = (const float*)d_in[1];
    const float* gumbel     = (const float*)d_in[2];
    const float* pre_w1     = (const float*)d_in[3];
    const float* pre_b1     = (const float*)d_in[4];
    const float* pre_w2     = (const float*)d_in[5];
    const float* pre_b2     = (const float*)d_in[6];
    const float* placeholder= (const float*)d_in[7];
    const float* emb_w      = (const float*)d_in[8];
    const float* emb_b      = (const float*)d_in[9];
    const float* ln1_g      = (const float*)d_in[10];
    const float* ln1_b      = (const float*)d_in[11];
    const float* attn_bias  = (const float*)d_in[12];
    const float* pt_w1      = (const float*)d_in[13];
    const float* pt_b1      = (const float*)d_in[14];
    const float* pt_w2      = (const float*)d_in[15];
    const float* pt_b2      = (const float*)d_in[16];
    const float* px_w       = (const float*)d_in[17];
    const float* px_b       = (const float*)d_in[18];
    const float* ps_w       = (const float*)d_in[19];
    const float* ps_b       = (const float*)d_in[20];
    const float* q_w        = (const float*)d_in[21];
    const float* k_w        = (const float*)d_in[22];
    const float* v_w        = (const float*)d_in[23];
    const float* o_w        = (const float*)d_in[24];
    const float* o_b        = (const float*)d_in[25];
    const float* ln2_g      = (const float*)d_in[26];
    const float* ln2_b      = (const float*)d_in[27];
    const float* mlp_w1     = (const float*)d_in[28];
    const float* mlp_b1     = (const float*)d_in[29];
    const float* mlp_w2     = (const float*)d_in[30];
    const float* mlp_b2     = (const float*)d_in[31];
    const float* ln3_g      = (const float*)d_in[32];
    const float* ln3_b      = (const float*)d_in[33];
    const float* head_w     = (const float*)d_in[34];
    const float* head_b     = (const float*)d_in[35];

    float* ws   = (float*)d_ws;
    float* fx   = ws;                                   // NT*HID
    float* scr  = fx  + (size_t)NT*HID;                 // NT*HID (xm / ox / t)
    float* sw   = scr + (size_t)NT*HID;                 // B*H*N*G
    float* mu   = sw  + (size_t)BB*HH*NN*GG;            // NT
    float* rstd = mu  + NT;                             // NT
    float* st   = rstd+ NT;                             // B*H*G*DH = 32768
    float* nrm  = st  + BB*HH*GG*DHH;                   // 1024
    float* o    = nrm + BB*HH*GG;                       // 32768
    float* wp   = o   + BB*HH*GG*DHH;                   // 10*WSEG

    dim3 blk(256);
    k_wprep<<<2*LL, blk, 0, stream>>>(px_w, px_b, ln1_g, ln1_b, mlp_w1, mlp_b1, ln2_g, ln2_b, wp);
    k_pre<<<NT/64, blk, 0, stream>>>(x, condition, pre_w1, pre_b1, pre_w2, pre_b2,
                                     placeholder, emb_w, emb_b, fx);
    for (int i = 0; i < LL; ++i) {
        float* wpx = wp + (size_t)(i*2 + 0)*WSEG;
        float* wm1 = wp + (size_t)(i*2 + 1)*WSEG;
        k_stats<<<NT/64, blk, 0, stream>>>(fx, mu, rstd);
        k_zero<<<(33792 + 255)/256, blk, 0, stream>>>(st, 33792);
        k_gemm<<<NT/64, blk, 0, stream>>>(fx, wpx, scr, mu, rstd,
                                          wpx + HID*HID, wpx + HID*HID + HID,
                                          nullptr, nullptr, 0);
        k_sw<<<BB*HH*64, blk, 0, stream>>>(scr, gumbel, pt_w1, pt_b1, pt_w2, pt_b2,
                                           ps_w, ps_b, attn_bias, sw, i);
        k_st<<<BB*HH*16, blk, 0, stream>>>(sw, scr, st, nrm);
        k_b<<<BB*HH, blk, 0, stream>>>(st, nrm, q_w, k_w, v_w, o, i);
        k_ox<<<NT/64, blk, 0, stream>>>(sw, o, scr);
        k_gemm<<<NT/64, blk, 0, stream>>>(scr, o_w + (size_t)i*HID*HID, fx,
                                          nullptr, nullptr, nullptr, nullptr,
                                          o_b + i*HID, fx, 2);
        k_stats<<<NT/64, blk, 0, stream>>>(fx, mu, rstd);
        k_gemm<<<NT/64, blk, 0, stream>>>(fx, wm1, scr, mu, rstd,
                                          wm1 + HID*HID, wm1 + HID*HID + HID,
                                          nullptr, nullptr, 1);
        k_gemm<<<NT/64, blk, 0, stream>>>(scr, mlp_w2 + (size_t)i*HID*HID, fx,
                                          nullptr, nullptr, nullptr, nullptr,
                                          mlp_b2 + i*HID, fx, 2);
    }
    k_stats<<<NT/64, blk, 0, stream>>>(fx, mu, rstd);
    k_head<<<NT/64, blk, 0, stream>>>(fx, mu, rstd, ln3_g, ln3_b, head_w, head_b, (float*)d_out);
}

// Round 5
// 4046.519 us; speedup vs baseline: 1.5159x; 1.5064x over previous
//
#include <hip/hip_runtime.h>
#include <math.h>

constexpr int LL  = 5;
constexpr int BB  = 4;
constexpr int NN  = 16384;
constexpr int HH  = 8;
constexpr int DHH = 32;
constexpr int GG  = 32;
constexpr int HID = 256;
constexpr int NT  = BB * NN;           // 65536 tokens
constexpr int WSEG = HID * HID + 2 * HID;  // 66048 floats per prepped matrix

__device__ __forceinline__ float gelu_f(float x) {
    return x * 0.5f * (1.0f + erff(x * 0.70710678118654752f));
}

// ---------------------------------------------------------------------------
// Prep: W' = g[k]*W[k,c]; u[c] = sum_k g[k]W[k,c]; cst[c] = sum_k b[k]W[k,c] + bias[c]
// grid = 10 blocks (layer*2 + {px, mlp1}), 256 threads
// ---------------------------------------------------------------------------
__global__ __launch_bounds__(256) void k_wprep(
    const float* __restrict__ px_w, const float* __restrict__ px_b,
    const float* __restrict__ ln1_g, const float* __restrict__ ln1_b,
    const float* __restrict__ mlp_w1, const float* __restrict__ mlp_b1,
    const float* __restrict__ ln2_g, const float* __restrict__ ln2_b,
    float* __restrict__ wp)
{
    int bid = blockIdx.x;
    int i = bid >> 1, which = bid & 1;
    const float *W, *g, *bln, *bias;
    if (which == 0) { W = px_w  + (size_t)i*HID*HID; g = ln1_g + i*HID; bln = ln1_b + i*HID; bias = px_b  + i*HID; }
    else            { W = mlp_w1+ (size_t)i*HID*HID; g = ln2_g + i*HID; bln = ln2_b + i*HID; bias = mlp_b1+ i*HID; }
    float* dst = wp + (size_t)bid * WSEG;
    float* u   = dst + HID*HID;
    float* cst = u + HID;
    int c = threadIdx.x;
    float au = 0.f, ac = 0.f;
    #pragma unroll 8
    for (int k = 0; k < HID; ++k) {
        float w  = W[k*HID + c];
        float gw = g[k] * w;
        dst[k*HID + c] = gw;
        au += gw;
        ac += bln[k] * w;
    }
    u[c] = au;
    cst[c] = ac + bias[c];
}

// ---------------------------------------------------------------------------
// Row stats (mean, rstd) over HID=256 for all NT tokens. grid = NT/64.
// ---------------------------------------------------------------------------
__global__ __launch_bounds__(256) void k_stats(
    const float* __restrict__ src, float* __restrict__ mu, float* __restrict__ rstd)
{
    int m0 = blockIdx.x * 64;
    int tid = threadIdx.x;
    int ml = tid >> 4, q = tid & 15;
    for (int it = 0; it < 4; ++it) {
        int m = m0 + it*16 + ml;
        const float* p = src + (size_t)m*HID + q*16;
        float s = 0.f, ss = 0.f;
        #pragma unroll
        for (int j = 0; j < 4; ++j) {
            float4 v = *(const float4*)(p + j*4);
            s  += v.x + v.y + v.z + v.w;
            ss += v.x*v.x + v.y*v.y + v.z*v.z + v.w*v.w;
        }
        #pragma unroll
        for (int off = 8; off >= 1; off >>= 1) {
            s  += __shfl_xor(s, off);
            ss += __shfl_xor(ss, off);
        }
        if (q == 0) {
            float mm = s * (1.f/HID);
            float vv = ss * (1.f/HID) - mm*mm;
            mu[m] = mm;
            rstd[m] = rsqrtf(vv + 1e-5f);
        }
    }
}

__global__ __launch_bounds__(256) void k_zero(float* __restrict__ p, int n)
{
    int i = blockIdx.x * 256 + threadIdx.x;
    if (i < n) p[i] = 0.f;
}

// ---------------------------------------------------------------------------
// Preprocess MLP: fx = gelu(x@pre_w1+b1)@pre_w2 + b2 + placeholder + cond_emb
// K = 512, tile 64 tokens x 256 channels. grid = NT/64.
// ---------------------------------------------------------------------------
__global__ __launch_bounds__(256) void k_pre(
    const float* __restrict__ x, const float* __restrict__ condition,
    const float* __restrict__ pre_w1, const float* __restrict__ pre_b1,
    const float* __restrict__ pre_w2, const float* __restrict__ pre_b2,
    const float* __restrict__ placeholder, const float* __restrict__ emb_w,
    const float* __restrict__ emb_b, float* __restrict__ fx)
{
    __shared__ float aT[32][68];
    __shared__ float wS[32][256];
    __shared__ float xs[128];
    int tid = threadIdx.x;
    int m0 = blockIdx.x * 64;
    int b = m0 / NN;
    if (tid < 128) xs[tid] = x[(size_t)m0*2 + tid];
    __syncthreads();
    float acc[4][16];
    #pragma unroll
    for (int a = 0; a < 4; ++a)
        #pragma unroll
        for (int c = 0; c < 16; ++c) acc[a][c] = 0.f;
    int tx = tid & 15, ty = tid >> 4;
    int lm = tid & 63, qq = tid >> 6;
    const float4* W4 = (const float4*)pre_w2;
    float4* wS4 = (float4*)&wS[0][0];
    float x0 = xs[lm*2], x1 = xs[lm*2 + 1];
    for (int kc = 0; kc < 512; kc += 32) {
        #pragma unroll
        for (int jj = 0; jj < 8; ++jj) {
            int kl = qq*8 + jj, k = kc + kl;
            aT[kl][lm] = gelu_f(x0*pre_w1[k] + x1*pre_w1[512 + k] + pre_b1[k]);
        }
        #pragma unroll
        for (int r = 0; r < 8; ++r) wS4[r*256 + tid] = W4[kc*64 + r*256 + tid];
        __syncthreads();
        #pragma unroll
        for (int k = 0; k < 32; ++k) {
            float4 av = *(const float4*)&aT[k][ty*4];
            #pragma unroll
            for (int ch = 0; ch < 4; ++ch) {
                float4 wv = *(const float4*)&wS[k][ch*64 + tx*4];
                acc[0][ch*4+0] += av.x*wv.x; acc[0][ch*4+1] += av.x*wv.y;
                acc[0][ch*4+2] += av.x*wv.z; acc[0][ch*4+3] += av.x*wv.w;
                acc[1][ch*4+0] += av.y*wv.x; acc[1][ch*4+1] += av.y*wv.y;
                acc[1][ch*4+2] += av.y*wv.z; acc[1][ch*4+3] += av.y*wv.w;
                acc[2][ch*4+0] += av.z*wv.x; acc[2][ch*4+1] += av.z*wv.y;
                acc[2][ch*4+2] += av.z*wv.z; acc[2][ch*4+3] += av.z*wv.w;
                acc[3][ch*4+0] += av.w*wv.x; acc[3][ch*4+1] += av.w*wv.y;
                acc[3][ch*4+2] += av.w*wv.z; acc[3][ch*4+3] += av.w*wv.w;
            }
        }
        __syncthreads();
    }
    float c0 = condition[b*3+0], c1 = condition[b*3+1], c2 = condition[b*3+2];
    #pragma unroll
    for (int ch = 0; ch < 4; ++ch) {
        int cbase = ch*64 + tx*4;
        float e[4];
        #pragma unroll
        for (int j = 0; j < 4; ++j) {
            int c = cbase + j;
            e[j] = pre_b2[c] + placeholder[c] + emb_b[c]
                 + c0*emb_w[c] + c1*emb_w[HID + c] + c2*emb_w[2*HID + c];
        }
        #pragma unroll
        for (int mi = 0; mi < 4; ++mi) {
            int m = m0 + ty*4 + mi;
            float4 o4 = make_float4(acc[mi][ch*4+0]+e[0], acc[mi][ch*4+1]+e[1],
                                    acc[mi][ch*4+2]+e[2], acc[mi][ch*4+3]+e[3]);
            *(float4*)&fx[(size_t)m*HID + cbase] = o4;
        }
    }
}

// ---------------------------------------------------------------------------
// Generic K=256 GEMM, tile 64x256, grid NT/64.
// mode 0: out = rstd*(acc - mu*u[c]) + cst[c]           (LN-folded, A1)
// mode 1: same + gelu                                    (C2)
// mode 2: out = acc + bias[c] + res[m][c]                (C1/C3 residual)
// ---------------------------------------------------------------------------
__global__ __launch_bounds__(256) void k_gemm(
    const float* __restrict__ A, const float* __restrict__ W,
    float* __restrict__ out,
    const float* __restrict__ mu, const float* __restrict__ rstd,
    const float* __restrict__ u, const float* __restrict__ cst,
    const float* __restrict__ bias, const float* __restrict__ res,
    int mode)
{
    __shared__ float aT[32][68];
    __shared__ float wS[32][256];
    int tid = threadIdx.x;
    int m0 = blockIdx.x * 64;
    int tx = tid & 15, ty = tid >> 4;
    int lm = tid >> 2, qc = (tid & 3) * 8;
    float acc[4][16];
    #pragma unroll
    for (int a = 0; a < 4; ++a)
        #pragma unroll
        for (int c = 0; c < 16; ++c) acc[a][c] = 0.f;
    const float4* W4 = (const float4*)W;
    float4* wS4 = (float4*)&wS[0][0];
    for (int kc = 0; kc < 256; kc += 32) {
        const float* ap = A + (size_t)(m0 + lm)*HID + kc + qc;
        float4 v0 = *(const float4*)ap;
        float4 v1 = *(const float4*)(ap + 4);
        aT[qc+0][lm] = v0.x; aT[qc+1][lm] = v0.y; aT[qc+2][lm] = v0.z; aT[qc+3][lm] = v0.w;
        aT[qc+4][lm] = v1.x; aT[qc+5][lm] = v1.y; aT[qc+6][lm] = v1.z; aT[qc+7][lm] = v1.w;
        #pragma unroll
        for (int r = 0; r < 8; ++r) wS4[r*256 + tid] = W4[kc*64 + r*256 + tid];
        __syncthreads();
        #pragma unroll
        for (int k = 0; k < 32; ++k) {
            float4 av = *(const float4*)&aT[k][ty*4];
            #pragma unroll
            for (int ch = 0; ch < 4; ++ch) {
                float4 wv = *(const float4*)&wS[k][ch*64 + tx*4];
                acc[0][ch*4+0] += av.x*wv.x; acc[0][ch*4+1] += av.x*wv.y;
                acc[0][ch*4+2] += av.x*wv.z; acc[0][ch*4+3] += av.x*wv.w;
                acc[1][ch*4+0] += av.y*wv.x; acc[1][ch*4+1] += av.y*wv.y;
                acc[1][ch*4+2] += av.y*wv.z; acc[1][ch*4+3] += av.y*wv.w;
                acc[2][ch*4+0] += av.z*wv.x; acc[2][ch*4+1] += av.z*wv.y;
                acc[2][ch*4+2] += av.z*wv.z; acc[2][ch*4+3] += av.z*wv.w;
                acc[3][ch*4+0] += av.w*wv.x; acc[3][ch*4+1] += av.w*wv.y;
                acc[3][ch*4+2] += av.w*wv.z; acc[3][ch*4+3] += av.w*wv.w;
            }
        }
        __syncthreads();
    }
    int mbase = m0 + ty*4;
    if (mode == 2) {
        #pragma unroll
        for (int ch = 0; ch < 4; ++ch) {
            int cbase = ch*64 + tx*4;
            float4 bv = *(const float4*)&bias[cbase];
            #pragma unroll
            for (int mi = 0; mi < 4; ++mi) {
                float4 rv = *(const float4*)&res[(size_t)(mbase + mi)*HID + cbase];
                float4 o4 = make_float4(acc[mi][ch*4+0] + bv.x + rv.x,
                                        acc[mi][ch*4+1] + bv.y + rv.y,
                                        acc[mi][ch*4+2] + bv.z + rv.z,
                                        acc[mi][ch*4+3] + bv.w + rv.w);
                *(float4*)&out[(size_t)(mbase + mi)*HID + cbase] = o4;
            }
        }
    } else {
        float mu_[4], rs_[4];
        #pragma unroll
        for (int mi = 0; mi < 4; ++mi) { mu_[mi] = mu[mbase+mi]; rs_[mi] = rstd[mbase+mi]; }
        #pragma unroll
        for (int ch = 0; ch < 4; ++ch) {
            int cbase = ch*64 + tx*4;
            float4 uv = *(const float4*)&u[cbase];
            float4 cv = *(const float4*)&cst[cbase];
            #pragma unroll
            for (int mi = 0; mi < 4; ++mi) {
                float4 o4;
                o4.x = rs_[mi]*(acc[mi][ch*4+0] - mu_[mi]*uv.x) + cv.x;
                o4.y = rs_[mi]*(acc[mi][ch*4+1] - mu_[mi]*uv.y) + cv.y;
                o4.z = rs_[mi]*(acc[mi][ch*4+2] - mu_[mi]*uv.z) + cv.z;
                o4.w = rs_[mi]*(acc[mi][ch*4+3] - mu_[mi]*uv.w) + cv.w;
                if (mode == 1) {
                    o4.x = gelu_f(o4.x); o4.y = gelu_f(o4.y);
                    o4.z = gelu_f(o4.z); o4.w = gelu_f(o4.w);
                }
                *(float4*)&out[(size_t)(mbase + mi)*HID + cbase] = o4;
            }
        }
    }
}

// ---------------------------------------------------------------------------
// k_pt (R4 = R3 + gumbel sign fix): one GEMM over M = NT*H rows (xm viewed
// [512K,32]), W = [pt_w1 | ps_w] (32x64), fused temp + gumbel-softmax
// epilogue via in-wave shuffles. Tile 64 rows x 64 cols, acc 4x4/thread.
// R3 BUG: wrote "- __logf(X)*-1.f" = +log(X); reference gn = -log(X).
// ---------------------------------------------------------------------------
__global__ __launch_bounds__(256) void k_pt(
    const float* __restrict__ xm, const float* __restrict__ gumbel,
    const float* __restrict__ pt_w1, const float* __restrict__ pt_b1,
    const float* __restrict__ pt_w2, const float* __restrict__ pt_b2,
    const float* __restrict__ ps_w, const float* __restrict__ ps_b,
    const float* __restrict__ attn_bias, float* __restrict__ sw, int layer)
{
    __shared__ float aT[32][68];
    __shared__ float w_l[32][64];
    int tid = threadIdx.x;
    int m0 = blockIdx.x * 64;               // row = (b*NN + n)*8 + h
    int tx = tid & 15, ty = tid >> 4;
    {
        int row = tid >> 2, cb = (tid & 3) * 8;
        const float* ap = xm + (size_t)(m0 + row)*DHH + cb;
        float4 v0 = *(const float4*)ap, v1 = *(const float4*)(ap + 4);
        aT[cb+0][row] = v0.x; aT[cb+1][row] = v0.y; aT[cb+2][row] = v0.z; aT[cb+3][row] = v0.w;
        aT[cb+4][row] = v1.x; aT[cb+5][row] = v1.y; aT[cb+6][row] = v1.z; aT[cb+7][row] = v1.w;
        int kk = tid >> 3, seg = tid & 7;
        const float* wsrc = (seg < 4) ? (pt_w1 + layer*DHH*GG + kk*GG + seg*8)
                                      : (ps_w  + layer*DHH*GG + kk*GG + (seg-4)*8);
        *(float4*)&w_l[kk][seg*8]     = *(const float4*)wsrc;
        *(float4*)&w_l[kk][seg*8 + 4] = *(const float4*)(wsrc + 4);
    }
    __syncthreads();
    float acc[4][4];
    #pragma unroll
    for (int i = 0; i < 4; ++i)
        #pragma unroll
        for (int j = 0; j < 4; ++j) acc[i][j] = 0.f;
    #pragma unroll
    for (int k = 0; k < 32; ++k) {
        float4 av = *(const float4*)&aT[k][ty*4];
        float4 wv = *(const float4*)&w_l[k][tx*4];
        acc[0][0] += av.x*wv.x; acc[0][1] += av.x*wv.y; acc[0][2] += av.x*wv.z; acc[0][3] += av.x*wv.w;
        acc[1][0] += av.y*wv.x; acc[1][1] += av.y*wv.y; acc[1][2] += av.y*wv.z; acc[1][3] += av.y*wv.w;
        acc[2][0] += av.z*wv.x; acc[2][1] += av.z*wv.y; acc[2][2] += av.z*wv.z; acc[2][3] += av.z*wv.w;
        acc[3][0] += av.w*wv.x; acc[3][1] += av.w*wv.y; acc[3][2] += av.w*wv.z; acc[3][3] += av.w*wv.w;
    }
    int mbase = m0 + ty*4;
    float s[4] = {0.f, 0.f, 0.f, 0.f};
    if (tx < 8) {
        float4 b1 = *(const float4*)(pt_b1 + layer*GG + tx*4);
        float4 w2 = *(const float4*)(pt_w2 + layer*GG + tx*4);
        #pragma unroll
        for (int mi = 0; mi < 4; ++mi) {
            s[mi] = gelu_f(acc[mi][0] + b1.x) * w2.x + gelu_f(acc[mi][1] + b1.y) * w2.y
                  + gelu_f(acc[mi][2] + b1.z) * w2.z + gelu_f(acc[mi][3] + b1.w) * w2.w;
        }
    }
    #pragma unroll
    for (int mi = 0; mi < 4; ++mi) {
        #pragma unroll
        for (int off = 1; off <= 4; off <<= 1) s[mi] += __shfl_xor(s[mi], off);
        s[mi] += __shfl_xor(s[mi], 8);   // broadcast to high half
    }
    float ptb2 = pt_b2[layer];
    if (tx >= 8) {
        int g0 = (tx - 8) * 4;
        float4 psb = *(const float4*)(ps_b + layer*GG + g0);
        float ev[4][4], mx[4], sm[4];
        #pragma unroll
        for (int mi = 0; mi < 4; ++mi) {
            int row = mbase + mi;
            int h = row & 7, n = (row >> 3) & (NN - 1), b = row >> 17;  // NN*8 = 2^17
            float ab = attn_bias[layer*HH + h];
            float rt = 1.f / fmaxf(gelu_f(s[mi] + ptb2) + ab, 0.01f);
            float4 gv = *(const float4*)(gumbel +
                ((((size_t)layer*BB + b)*HH + h)*NN + n)*GG + g0);
            // gn = -log(-log(u+1e-8)+1e-8); logit = (acc + psb + gn) * rt
            float l0 = (acc[mi][0] + psb.x - __logf(-__logf(gv.x + 1e-8f) + 1e-8f)) * rt;
            float l1 = (acc[mi][1] + psb.y - __logf(-__logf(gv.y + 1e-8f) + 1e-8f)) * rt;
            float l2 = (acc[mi][2] + psb.z - __logf(-__logf(gv.z + 1e-8f) + 1e-8f)) * rt;
            float l3 = (acc[mi][3] + psb.w - __logf(-__logf(gv.w + 1e-8f) + 1e-8f)) * rt;
            float m01 = fmaxf(l0, l1), m23 = fmaxf(l2, l3);
            mx[mi] = fmaxf(m01, m23);
            ev[mi][0] = l0; ev[mi][1] = l1; ev[mi][2] = l2; ev[mi][3] = l3;
        }
        #pragma unroll
        for (int mi = 0; mi < 4; ++mi) {
            #pragma unroll
            for (int off = 1; off <= 4; off <<= 1) mx[mi] = fmaxf(mx[mi], __shfl_xor(mx[mi], off));
            float e0 = __expf(ev[mi][0] - mx[mi]);
            float e1 = __expf(ev[mi][1] - mx[mi]);
            float e2 = __expf(ev[mi][2] - mx[mi]);
            float e3 = __expf(ev[mi][3] - mx[mi]);
            ev[mi][0] = e0; ev[mi][1] = e1; ev[mi][2] = e2; ev[mi][3] = e3;
            sm[mi] = e0 + e1 + e2 + e3;
            #pragma unroll
            for (int off = 1; off <= 4; off <<= 1) sm[mi] += __shfl_xor(sm[mi], off);
        }
        #pragma unroll
        for (int mi = 0; mi < 4; ++mi) {
            int row = mbase + mi;
            int h = row & 7, n = (row >> 3) & (NN - 1), b = row >> 17;
            float inv = 1.f / sm[mi];
            *(float4*)(sw + (((size_t)(b*HH + h))*NN + n)*GG + g0) =
                make_float4(ev[mi][0]*inv, ev[mi][1]*inv, ev[mi][2]*inv, ev[mi][3]*inv);
        }
    }
}

// ---------------------------------------------------------------------------
// k_st: st[bh][g][c] = sum_n sw[bh][n][g]*xm[b][n][h*32+c]; nrm = sum sw.
// 32x32 outer-product GEMM per (b,h): 512 blocks (32 bh x 16 chunks of 1024
// tokens). 4x4 register tile per lane; LDS merge; spread atomics.
// ---------------------------------------------------------------------------
__global__ __launch_bounds__(256) void k_st(
    const float* __restrict__ sw, const float* __restrict__ xm,
    float* __restrict__ st, float* __restrict__ nrm)
{
    __shared__ float sw_l[1024];
    __shared__ float xm_l[1024];
    __shared__ float part[4096];
    int tid = threadIdx.x;
    int bh = blockIdx.x >> 4;
    int b = bh >> 3, h = bh & 7;
    int n0 = (blockIdx.x & 15) << 10;
    int w = tid >> 6, lane = tid & 63;
    int g0 = (lane & 7) * 4, c0 = (lane >> 3) * 4;
    int row = tid >> 3, col4 = (tid & 7) * 4;
    float acc[4][4];
    #pragma unroll
    for (int i = 0; i < 4; ++i)
        #pragma unroll
        for (int j = 0; j < 4; ++j) acc[i][j] = 0.f;
    float nacc[4] = {0.f, 0.f, 0.f, 0.f};

    for (int t8 = 0; t8 < 32; ++t8) {
        int nb = n0 + t8*32;
        *(float4*)&sw_l[tid*4] = ((const float4*)(sw + ((size_t)bh*NN + nb)*GG))[tid];
        *(float4*)&xm_l[tid*4] = *(const float4*)(xm + (size_t)(b*NN + nb + row)*HID + h*DHH + col4);
        __syncthreads();
        #pragma unroll
        for (int tt = 0; tt < 8; ++tt) {
            int t = w*8 + tt;
            float4 a  = *(float4*)&sw_l[t*32 + g0];
            float4 xv = *(float4*)&xm_l[t*32 + c0];
            acc[0][0] += a.x*xv.x; acc[0][1] += a.x*xv.y; acc[0][2] += a.x*xv.z; acc[0][3] += a.x*xv.w;
            acc[1][0] += a.y*xv.x; acc[1][1] += a.y*xv.y; acc[1][2] += a.y*xv.z; acc[1][3] += a.y*xv.w;
            acc[2][0] += a.z*xv.x; acc[2][1] += a.z*xv.y; acc[2][2] += a.z*xv.z; acc[2][3] += a.z*xv.w;
            acc[3][0] += a.w*xv.x; acc[3][1] += a.w*xv.y; acc[3][2] += a.w*xv.z; acc[3][3] += a.w*xv.w;
            nacc[0] += a.x; nacc[1] += a.y; nacc[2] += a.z; nacc[3] += a.w;
        }
        __syncthreads();
    }
    #pragma unroll
    for (int i = 0; i < 4; ++i)
        *(float4*)&part[w*1024 + (g0+i)*32 + c0] =
            make_float4(acc[i][0], acc[i][1], acc[i][2], acc[i][3]);
    __syncthreads();
    #pragma unroll
    for (int r = 0; r < 4; ++r) {
        int idx = r*256 + tid;
        float v = part[idx] + part[1024+idx] + part[2048+idx] + part[3072+idx];
        atomicAdd(&st[(size_t)bh*GG*DHH + idx], v);
    }
    if ((lane >> 3) == 0) {
        #pragma unroll
        for (int i = 0; i < 4; ++i)
            atomicAdd(&nrm[bh*GG + g0 + i], nacc[i]);
    }
}

// ---------------------------------------------------------------------------
// B: slice-token attention per (b,h). grid = B*H = 32 blocks.
// ---------------------------------------------------------------------------
__global__ __launch_bounds__(256) void k_b(
    const float* __restrict__ st, const float* __restrict__ nrm,
    const float* __restrict__ q_w, const float* __restrict__ k_w, const float* __restrict__ v_w,
    float* __restrict__ o, int layer)
{
    __shared__ float st_l[32][33], q_l[32][33], k_l[32][33], v_l[32][33], a_l[32][33];
    __shared__ float wq[32][32], wk[32][32], wv[32][32];
    int tid = threadIdx.x;
    int bh = blockIdx.x;
    #pragma unroll
    for (int r = 0; r < 4; ++r) {
        ((float*)wq)[r*256 + tid] = q_w[(size_t)layer*DHH*DHH + r*256 + tid];
        ((float*)wk)[r*256 + tid] = k_w[(size_t)layer*DHH*DHH + r*256 + tid];
        ((float*)wv)[r*256 + tid] = v_w[(size_t)layer*DHH*DHH + r*256 + tid];
    }
    #pragma unroll
    for (int r = 0; r < 4; ++r) {
        int idx = r*256 + tid;
        int gg2 = idx >> 5, cc = idx & 31;
        st_l[gg2][cc] = st[(size_t)bh*GG*DHH + idx] / (nrm[bh*GG + gg2] + 1e-5f);
    }
    __syncthreads();
    int g2 = tid >> 3, c4 = (tid & 7) * 4;
    float aq[4] = {0,0,0,0}, ak[4] = {0,0,0,0}, avv[4] = {0,0,0,0};
    #pragma unroll
    for (int k = 0; k < 32; ++k) {
        float sv = st_l[g2][k];
        #pragma unroll
        for (int j = 0; j < 4; ++j) {
            aq[j]  += sv * wq[k][c4+j];
            ak[j]  += sv * wk[k][c4+j];
            avv[j] += sv * wv[k][c4+j];
        }
    }
    #pragma unroll
    for (int j = 0; j < 4; ++j) { q_l[g2][c4+j] = aq[j]; k_l[g2][c4+j] = ak[j]; v_l[g2][c4+j] = avv[j]; }
    __syncthreads();
    if (tid < 32) {
        int gq = tid;
        float sc[32];
        float mx = -1e30f;
        #pragma unroll
        for (int j = 0; j < 32; ++j) {
            float s2 = 0.f;
            #pragma unroll
            for (int c = 0; c < 32; ++c) s2 += q_l[gq][c] * k_l[j][c];
            s2 *= 0.17677669529663687f;  // 1/sqrt(32)
            sc[j] = s2;
            mx = fmaxf(mx, s2);
        }
        float se = 0.f;
        #pragma unroll
        for (int j = 0; j < 32; ++j) { sc[j] = __expf(sc[j] - mx); se += sc[j]; }
        float inv = 1.f / se;
        #pragma unroll
        for (int j = 0; j < 32; ++j) a_l[gq][j] = sc[j] * inv;
    }
    __syncthreads();
    float ao[4] = {0,0,0,0};
    #pragma unroll
    for (int k2 = 0; k2 < 32; ++k2) {
        float aw = a_l[g2][k2];
        #pragma unroll
        for (int j = 0; j < 4; ++j) ao[j] += aw * v_l[k2][c4+j];
    }
    #pragma unroll
    for (int j = 0; j < 4; ++j) o[(size_t)bh*GG*DHH + g2*DHH + c4 + j] = ao[j];
}

// ---------------------------------------------------------------------------
// ox scatter-back: ox[n, h*32+c] = sum_g o[b,h,g,c] * sw[b,h,n,g]. grid NT/64.
// ---------------------------------------------------------------------------
__global__ __launch_bounds__(256) void k_ox(
    const float* __restrict__ sw, const float* __restrict__ o, float* __restrict__ ox)
{
    __shared__ float o_l[8192];
    __shared__ float sw_l[16][256];
    int tid = threadIdx.x;
    int m0 = blockIdx.x * 64;
    int b = m0 / NN;
    int n0 = m0 % NN;
    int h = tid >> 5, c = tid & 31;
    #pragma unroll
    for (int r = 0; r < 32; ++r) o_l[r*256 + tid] = o[(size_t)b*HH*GG*DHH + r*256 + tid];
    __syncthreads();
    for (int mc = 0; mc < 4; ++mc) {
        #pragma unroll
        for (int r = 0; r < 16; ++r)
            sw_l[r][tid] = sw[(size_t)((b*HH + h)*NN + n0 + mc*16 + r)*GG + c];
        __syncthreads();
        for (int ml = 0; ml < 16; ++ml) {
            float acc2 = 0.f;
            #pragma unroll
            for (int gg2 = 0; gg2 < 32; ++gg2)
                acc2 += sw_l[ml][h*32 + gg2] * o_l[(h*32 + gg2)*32 + c];
            ox[(size_t)(m0 + mc*16 + ml)*HID + tid] = acc2;
        }
        __syncthreads();
    }
}

// ---------------------------------------------------------------------------
// Head: out = LN3(fx) @ head_w + head_b. grid NT/64.
// ---------------------------------------------------------------------------
__global__ __launch_bounds__(256) void k_head(
    const float* __restrict__ fx, const float* __restrict__ mu, const float* __restrict__ rstd,
    const float* __restrict__ g3, const float* __restrict__ b3,
    const float* __restrict__ hw, const float* __restrict__ hb,
    float* __restrict__ out)
{
    __shared__ float fx_l[64][257];
    int tid = threadIdx.x;
    int m0 = blockIdx.x * 64;
    for (int r = 0; r < 64; ++r) fx_l[r][tid] = fx[(size_t)(m0 + r)*HID + tid];
    __syncthreads();
    int ml = tid & 63, oo = tid >> 6;
    float mu_ = mu[m0 + ml], rs_ = rstd[m0 + ml];
    float acc2 = hb[oo];
    #pragma unroll 8
    for (int k = 0; k < HID; ++k) {
        float hv = (fx_l[ml][k] - mu_) * rs_ * g3[k] + b3[k];
        acc2 += hv * hw[k*4 + oo];
    }
    out[(size_t)(m0 + ml)*4 + oo] = acc2;
}

// ---------------------------------------------------------------------------
extern "C" void kernel_launch(void* const* d_in, const int* in_sizes, int n_in,
                              void* d_out, int out_size, void* d_ws, size_t ws_size,
                              hipStream_t stream)
{
    (void)in_sizes; (void)n_in; (void)out_size; (void)ws_size;
    const float* x          = (const float*)d_in[0];
    const float* condition  = (const float*)d_in[1];
    const float* gumbel     = (const float*)d_in[2];
    const float* pre_w1     = (const float*)d_in[3];
    const float* pre_b1     = (const float*)d_in[4];
    const float* pre_w2     = (const float*)d_in[5];
    const float* pre_b2     = (const float*)d_in[6];
    const float* placeholder= (const float*)d_in[7];
    const float* emb_w      = (const float*)d_in[8];
    const float* emb_b      = (const float*)d_in[9];
    const float* ln1_g      = (const float*)d_in[10];
    const float* ln1_b      = (const float*)d_in[11];
    const float* attn_bias  = (const float*)d_in[12];
    const float* pt_w1      = (const float*)d_in[13];
    const float* pt_b1      = (const float*)d_in[14];
    const float* pt_w2      = (const float*)d_in[15];
    const float* pt_b2      = (const float*)d_in[16];
    const float* px_w       = (const float*)d_in[17];
    const float* px_b       = (const float*)d_in[18];
    const float* ps_w       = (const float*)d_in[19];
    const float* ps_b       = (const float*)d_in[20];
    const float* q_w        = (const float*)d_in[21];
    const float* k_w        = (const float*)d_in[22];
    const float* v_w        = (const float*)d_in[23];
    const float* o_w        = (const float*)d_in[24];
    const float* o_b        = (const float*)d_in[25];
    const float* ln2_g      = (const float*)d_in[26];
    const float* ln2_b      = (const float*)d_in[27];
    const float* mlp_w1     = (const float*)d_in[28];
    const float* mlp_b1     = (const float*)d_in[29];
    const float* mlp_w2     = (const float*)d_in[30];
    const float* mlp_b2     = (const float*)d_in[31];
    const float* ln3_g      = (const float*)d_in[32];
    const float* ln3_b      = (const float*)d_in[33];
    const float* head_w     = (const float*)d_in[34];
    const float* head_b     = (const float*)d_in[35];

    float* ws   = (float*)d_ws;
    float* fx   = ws;                                   // NT*HID
    float* scr  = fx  + (size_t)NT*HID;                 // NT*HID (xm / ox / t)
    float* sw   = scr + (size_t)NT*HID;                 // B*H*N*G
    float* mu   = sw  + (size_t)BB*HH*NN*GG;            // NT
    float* rstd = mu  + NT;                             // NT
    float* st   = rstd+ NT;                             // B*H*G*DH = 32768
    float* nrm  = st  + BB*HH*GG*DHH;                   // 1024
    float* o    = nrm + BB*HH*GG;                       // 32768
    float* wp   = o   + BB*HH*GG*DHH;                   // 10*WSEG

    dim3 blk(256);
    k_wprep<<<2*LL, blk, 0, stream>>>(px_w, px_b, ln1_g, ln1_b, mlp_w1, mlp_b1, ln2_g, ln2_b, wp);
    k_pre<<<NT/64, blk, 0, stream>>>(x, condition, pre_w1, pre_b1, pre_w2, pre_b2,
                                     placeholder, emb_w, emb_b, fx);
    for (int i = 0; i < LL; ++i) {
        float* wpx = wp + (size_t)(i*2 + 0)*WSEG;
        float* wm1 = wp + (size_t)(i*2 + 1)*WSEG;
        k_stats<<<NT/64, blk, 0, stream>>>(fx, mu, rstd);
        k_zero<<<(33792 + 255)/256, blk, 0, stream>>>(st, 33792);
        k_gemm<<<NT/64, blk, 0, stream>>>(fx, wpx, scr, mu, rstd,
                                          wpx + HID*HID, wpx + HID*HID + HID,
                                          nullptr, nullptr, 0);
        k_pt<<<NT*HH/64, blk, 0, stream>>>(scr, gumbel, pt_w1, pt_b1, pt_w2, pt_b2,
                                           ps_w, ps_b, attn_bias, sw, i);
        k_st<<<BB*HH*16, blk, 0, stream>>>(sw, scr, st, nrm);
        k_b<<<BB*HH, blk, 0, stream>>>(st, nrm, q_w, k_w, v_w, o, i);
        k_ox<<<NT/64, blk, 0, stream>>>(sw, o, scr);
        k_gemm<<<NT/64, blk, 0, stream>>>(scr, o_w + (size_t)i*HID*HID, fx,
                                          nullptr, nullptr, nullptr, nullptr,
                                          o_b + i*HID, fx, 2);
        k_stats<<<NT/64, blk, 0, stream>>>(fx, mu, rstd);
        k_gemm<<<NT/64, blk, 0, stream>>>(fx, wm1, scr, mu, rstd,
                                          wm1 + HID*HID, wm1 + HID*HID + HID,
                                          nullptr, nullptr, 1);
        k_gemm<<<NT/64, blk, 0, stream>>>(scr, mlp_w2 + (size_t)i*HID*HID, fx,
                                          nullptr, nullptr, nullptr, nullptr,
                                          mlp_b2 + i*HID, fx, 2);
    }
    k_stats<<<NT/64, blk, 0, stream>>>(fx, mu, rstd);
    k_head<<<NT/64, blk, 0, stream>>>(fx, mu, rstd, ln3_g, ln3_b, head_w, head_b, (float*)d_out);
}

// Round 6
// 2349.991 us; speedup vs baseline: 2.6102x; 1.7219x over previous
//
#include <hip/hip_runtime.h>
#include <math.h>

constexpr int LL  = 5;
constexpr int BB  = 4;
constexpr int NN  = 16384;
constexpr int HH  = 8;
constexpr int DHH = 32;
constexpr int GG  = 32;
constexpr int HID = 256;
constexpr int NT  = BB * NN;           // 65536 tokens

typedef __attribute__((ext_vector_type(8))) short short8;   // 8 bf16 (4 VGPR)
typedef __attribute__((ext_vector_type(4))) float f32x4;    // MFMA acc

__device__ __forceinline__ float gelu_f(float x) {
    return x * 0.5f * (1.0f + erff(x * 0.70710678118654752f));
}
__device__ __forceinline__ uint f2b(float x) {   // fp32 -> bf16 bits, RNE
    uint u = __float_as_uint(x);
    return (u + 0x7FFFu + ((u >> 16) & 1u)) >> 16;
}

// ---------------------------------------------------------------------------
// Prep (LN-folded px/mlp1): Wtb[(k/32)][c][k%32] = bf16(g[k]*W[k][c]);
// u[c] = sum_k g[k]W[k][c]; cst[c] = sum_k b[k]W[k][c] + bias[c].
// grid = 10 (layer*2 + {px,mlp1}), 256 thr. Writes coalesced 64B/thread.
// ---------------------------------------------------------------------------
__global__ __launch_bounds__(256) void k_wprep(
    const float* __restrict__ px_w, const float* __restrict__ px_b,
    const float* __restrict__ ln1_g, const float* __restrict__ ln1_b,
    const float* __restrict__ mlp_w1, const float* __restrict__ mlp_b1,
    const float* __restrict__ ln2_g, const float* __restrict__ ln2_b,
    ushort* __restrict__ wq, float* __restrict__ ucst)
{
    int bid = blockIdx.x;
    int i = bid >> 1, which = bid & 1;
    const float *W, *g, *bln, *bias;
    if (which == 0) { W = px_w  + (size_t)i*HID*HID; g = ln1_g + i*HID; bln = ln1_b + i*HID; bias = px_b  + i*HID; }
    else            { W = mlp_w1+ (size_t)i*HID*HID; g = ln2_g + i*HID; bln = ln2_b + i*HID; bias = mlp_b1+ i*HID; }
    ushort* dst = wq + (size_t)bid * 65536;
    float*  u   = ucst + (size_t)bid * 512;
    float*  cst = u + 256;
    int c = threadIdx.x;
    float au = 0.f, ac = 0.f;
    for (int kg = 0; kg < 8; ++kg) {
        uint b2[16];
        #pragma unroll
        for (int j = 0; j < 32; j += 2) {
            int k0 = kg*32 + j;
            float w0 = W[(size_t)k0*HID + c],  w1 = W[(size_t)(k0+1)*HID + c];
            float g0 = g[k0]*w0,              g1 = g[k0+1]*w1;
            au += g0 + g1;
            ac += bln[k0]*w0 + bln[k0+1]*w1;
            b2[j>>1] = f2b(g0) | (f2b(g1) << 16);
        }
        uint4* d4 = (uint4*)&dst[(size_t)kg*8192 + c*32];
        d4[0] = make_uint4(b2[0],b2[1],b2[2],b2[3]);
        d4[1] = make_uint4(b2[4],b2[5],b2[6],b2[7]);
        d4[2] = make_uint4(b2[8],b2[9],b2[10],b2[11]);
        d4[3] = make_uint4(b2[12],b2[13],b2[14],b2[15]);
    }
    u[c] = au;
    cst[c] = ac + bias[c];
}

// ---------------------------------------------------------------------------
// Convert o_w(5), mlp_w2(5), pre_w2(1) to transposed k-blocked bf16.
// grid = 96: [0,40) o_w, [40,80) mlp_w2, [80,96) pre_w2 (K=512 -> 16 kgroups)
// ---------------------------------------------------------------------------
__global__ __launch_bounds__(256) void k_wcvt(
    const float* __restrict__ o_w, const float* __restrict__ mlp_w2,
    const float* __restrict__ pre_w2,
    ushort* __restrict__ wo, ushort* __restrict__ wm2, ushort* __restrict__ wpre)
{
    int bid = blockIdx.x, c = threadIdx.x;
    const float* src; ushort* dst; int kg;
    if (bid < 40)      { int i = bid >> 3;        kg = bid & 7;        src = o_w    + (size_t)i*65536; dst = wo  + (size_t)i*65536; }
    else if (bid < 80) { int i = (bid - 40) >> 3; kg = (bid - 40) & 7; src = mlp_w2 + (size_t)i*65536; dst = wm2 + (size_t)i*65536; }
    else               { kg = bid - 80;           src = pre_w2;        dst = wpre; }
    uint b2[16];
    #pragma unroll
    for (int j = 0; j < 32; j += 2) {
        uint lo = f2b(src[(size_t)(kg*32 + j)*HID + c]);
        uint hi = f2b(src[(size_t)(kg*32 + j + 1)*HID + c]);
        b2[j>>1] = lo | (hi << 16);
    }
    uint4* d4 = (uint4*)&dst[(size_t)kg*8192 + c*32];
    d4[0] = make_uint4(b2[0],b2[1],b2[2],b2[3]);
    d4[1] = make_uint4(b2[4],b2[5],b2[6],b2[7]);
    d4[2] = make_uint4(b2[8],b2[9],b2[10],b2[11]);
    d4[3] = make_uint4(b2[12],b2[13],b2[14],b2[15]);
}

// ---------------------------------------------------------------------------
// Row stats + bf16 cast: mu/rstd over HID=256, fxh = bf16(fx). grid NT/64.
// ---------------------------------------------------------------------------
__global__ __launch_bounds__(256) void k_stats_cast(
    const float* __restrict__ src, float* __restrict__ mu, float* __restrict__ rstd,
    ushort* __restrict__ dsth)
{
    int m0 = blockIdx.x * 64;
    int tid = threadIdx.x;
    int ml = tid >> 4, q = tid & 15;
    for (int it = 0; it < 4; ++it) {
        int m = m0 + it*16 + ml;
        const float* p = src + (size_t)m*HID + q*16;
        float s = 0.f, ss = 0.f;
        uint pk[8];
        #pragma unroll
        for (int j = 0; j < 4; ++j) {
            float4 v = *(const float4*)(p + j*4);
            s  += v.x + v.y + v.z + v.w;
            ss += v.x*v.x + v.y*v.y + v.z*v.z + v.w*v.w;
            pk[j*2]   = f2b(v.x) | (f2b(v.y) << 16);
            pk[j*2+1] = f2b(v.z) | (f2b(v.w) << 16);
        }
        uint4* d = (uint4*)&dsth[(size_t)m*HID + q*16];
        d[0] = make_uint4(pk[0],pk[1],pk[2],pk[3]);
        d[1] = make_uint4(pk[4],pk[5],pk[6],pk[7]);
        #pragma unroll
        for (int off = 8; off >= 1; off >>= 1) {
            s  += __shfl_xor(s, off);
            ss += __shfl_xor(ss, off);
        }
        if (q == 0) {
            float mm = s * (1.f/HID);
            float vv = ss * (1.f/HID) - mm*mm;
            mu[m] = mm;
            rstd[m] = rsqrtf(vv + 1e-5f);
        }
    }
}

__global__ __launch_bounds__(256) void k_zero(float* __restrict__ p, int n)
{
    int i = blockIdx.x * 256 + threadIdx.x;
    if (i < n) p[i] = 0.f;
}

// ---------------------------------------------------------------------------
// MFMA GEMM: [64 x 256] tile, K=256, A bf16 [M,256], Wtb bf16 k-blocked.
// 4 waves; wave w owns cols [w*64, w*64+64): 4x4 of 16x16x32 MFMA, 64 acc.
// LDS rows padded to 40 shorts (16B-aligned, 2-way bank alias = free).
// mode 0: out_f = rstd*(acc - mu*u[c]) + cst[c]        (LN-folded -> xm)
// mode 1: out_h = bf16(gelu(same))                      (mlp1 -> t)
// mode 2: out_f = res + acc + bias[c]                   (residual -> fx)
// ---------------------------------------------------------------------------
__global__ __launch_bounds__(256) void k_mf(
    const ushort* __restrict__ A, const ushort* __restrict__ Wtb,
    float* __restrict__ out_f, ushort* __restrict__ out_h,
    const float* __restrict__ mu, const float* __restrict__ rstd,
    const float* __restrict__ u, const float* __restrict__ cst,
    const float* __restrict__ bias, const float* __restrict__ res,
    int mode)
{
    __shared__ __align__(16) short aS[64*40];
    __shared__ __align__(16) short bS[256*40];
    int tid = threadIdx.x;
    int m0 = blockIdx.x * 64;
    int w = tid >> 6, lane = tid & 63, quad = lane >> 4, l16 = lane & 15;
    int ar = tid >> 2, ach = tid & 3;
    f32x4 acc[4][4];
    #pragma unroll
    for (int mi = 0; mi < 4; ++mi)
        #pragma unroll
        for (int ni = 0; ni < 4; ++ni) acc[mi][ni] = (f32x4){0.f,0.f,0.f,0.f};

    for (int ks = 0; ks < 8; ++ks) {
        int kc = ks*32;
        *(uint4*)&aS[ar*40 + ach*8] =
            *(const uint4*)&A[(size_t)(m0 + ar)*HID + kc + ach*8];
        const ushort* bsrc = Wtb + (size_t)ks*8192;
        #pragma unroll
        for (int p = 0; p < 4; ++p) {
            int br = p*64 + ar;
            *(uint4*)&bS[br*40 + ach*8] = *(const uint4*)&bsrc[(size_t)br*32 + ach*8];
        }
        __syncthreads();
        short8 af[4], bfm[4];
        #pragma unroll
        for (int mi = 0; mi < 4; ++mi) af[mi]  = *(const short8*)&aS[(mi*16 + l16)*40 + quad*8];
        #pragma unroll
        for (int ni = 0; ni < 4; ++ni) bfm[ni] = *(const short8*)&bS[(w*64 + ni*16 + l16)*40 + quad*8];
        #pragma unroll
        for (int mi = 0; mi < 4; ++mi)
            #pragma unroll
            for (int ni = 0; ni < 4; ++ni)
                acc[mi][ni] = __builtin_amdgcn_mfma_f32_16x16x32_bf16(af[mi], bfm[ni], acc[mi][ni], 0, 0, 0);
        __syncthreads();
    }

    if (mode == 2) {
        #pragma unroll
        for (int mi = 0; mi < 4; ++mi) {
            int mr = m0 + mi*16 + quad*4;
            #pragma unroll
            for (int ni = 0; ni < 4; ++ni) {
                int c = w*64 + ni*16 + l16;
                float bc = bias[c];
                #pragma unroll
                for (int r = 0; r < 4; ++r) {
                    size_t idx = (size_t)(mr + r)*HID + c;
                    out_f[idx] = res[idx] + acc[mi][ni][r] + bc;
                }
            }
        }
    } else {
        #pragma unroll
        for (int mi = 0; mi < 4; ++mi) {
            int mr = m0 + mi*16 + quad*4;
            float mu4[4], rs4[4];
            #pragma unroll
            for (int r = 0; r < 4; ++r) { mu4[r] = mu[mr+r]; rs4[r] = rstd[mr+r]; }
            #pragma unroll
            for (int ni = 0; ni < 4; ++ni) {
                int c = w*64 + ni*16 + l16;
                float uc = u[c], cc = cst[c];
                #pragma unroll
                for (int r = 0; r < 4; ++r) {
                    size_t idx = (size_t)(mr + r)*HID + c;
                    float v = rs4[r]*(acc[mi][ni][r] - mu4[r]*uc) + cc;
                    if (mode == 1) out_h[idx] = (ushort)f2b(gelu_f(v));
                    else           out_f[idx] = v;
                }
            }
        }
    }
}

// ---------------------------------------------------------------------------
// Preprocess via MFMA: h1 = gelu(x@pre_w1+b1) built in-register -> bf16 LDS;
// fx = h1 @ pre_w2 (K=512) + b2 + placeholder + cond emb. grid NT/64.
// ---------------------------------------------------------------------------
__global__ __launch_bounds__(256) void k_pre_mf(
    const float* __restrict__ x, const float* __restrict__ condition,
    const float* __restrict__ pre_w1, const float* __restrict__ pre_b1,
    const ushort* __restrict__ wpre, const float* __restrict__ pre_b2,
    const float* __restrict__ placeholder, const float* __restrict__ emb_w,
    const float* __restrict__ emb_b, float* __restrict__ fx)
{
    __shared__ __align__(16) short aS[64*40];
    __shared__ __align__(16) short bS[256*40];
    __shared__ float xs[128];
    int tid = threadIdx.x;
    int m0 = blockIdx.x * 64;
    int b = m0 / NN;
    if (tid < 128) xs[tid] = x[(size_t)m0*2 + tid];
    __syncthreads();
    int w = tid >> 6, lane = tid & 63, quad = lane >> 4, l16 = lane & 15;
    int ar = tid >> 2, ach = tid & 3;
    float x0 = xs[ar*2], x1 = xs[ar*2 + 1];
    f32x4 acc[4][4];
    #pragma unroll
    for (int mi = 0; mi < 4; ++mi)
        #pragma unroll
        for (int ni = 0; ni < 4; ++ni) acc[mi][ni] = (f32x4){0.f,0.f,0.f,0.f};

    for (int ks = 0; ks < 16; ++ks) {
        int kc = ks*32;
        uint ab[4];
        #pragma unroll
        for (int j2 = 0; j2 < 4; ++j2) {
            int k = kc + ach*8 + j2*2;
            float h0 = gelu_f(x0*pre_w1[k]   + x1*pre_w1[512 + k]   + pre_b1[k]);
            float h1 = gelu_f(x0*pre_w1[k+1] + x1*pre_w1[512 + k+1] + pre_b1[k+1]);
            ab[j2] = f2b(h0) | (f2b(h1) << 16);
        }
        *(uint4*)&aS[ar*40 + ach*8] = make_uint4(ab[0], ab[1], ab[2], ab[3]);
        const ushort* bsrc = wpre + (size_t)ks*8192;
        #pragma unroll
        for (int p = 0; p < 4; ++p) {
            int br = p*64 + ar;
            *(uint4*)&bS[br*40 + ach*8] = *(const uint4*)&bsrc[(size_t)br*32 + ach*8];
        }
        __syncthreads();
        short8 af[4], bfm[4];
        #pragma unroll
        for (int mi = 0; mi < 4; ++mi) af[mi]  = *(const short8*)&aS[(mi*16 + l16)*40 + quad*8];
        #pragma unroll
        for (int ni = 0; ni < 4; ++ni) bfm[ni] = *(const short8*)&bS[(w*64 + ni*16 + l16)*40 + quad*8];
        #pragma unroll
        for (int mi = 0; mi < 4; ++mi)
            #pragma unroll
            for (int ni = 0; ni < 4; ++ni)
                acc[mi][ni] = __builtin_amdgcn_mfma_f32_16x16x32_bf16(af[mi], bfm[ni], acc[mi][ni], 0, 0, 0);
        __syncthreads();
    }
    float c0 = condition[b*3+0], c1 = condition[b*3+1], c2 = condition[b*3+2];
    #pragma unroll
    for (int ni = 0; ni < 4; ++ni) {
        int c = w*64 + ni*16 + l16;
        float e = pre_b2[c] + placeholder[c] + emb_b[c]
                + c0*emb_w[c] + c1*emb_w[HID + c] + c2*emb_w[2*HID + c];
        #pragma unroll
        for (int mi = 0; mi < 4; ++mi) {
            int mr = m0 + mi*16 + quad*4;
            #pragma unroll
            for (int r = 0; r < 4; ++r)
                fx[(size_t)(mr + r)*HID + c] = acc[mi][ni][r] + e;
        }
    }
}

// ---------------------------------------------------------------------------
// k_pt: GEMM over M = NT*H rows (xm viewed [512K,32]), W = [pt_w1 | ps_w],
// fused temp + gumbel-softmax epilogue via in-wave shuffles. (unchanged R4)
// ---------------------------------------------------------------------------
__global__ __launch_bounds__(256) void k_pt(
    const float* __restrict__ xm, const float* __restrict__ gumbel,
    const float* __restrict__ pt_w1, const float* __restrict__ pt_b1,
    const float* __restrict__ pt_w2, const float* __restrict__ pt_b2,
    const float* __restrict__ ps_w, const float* __restrict__ ps_b,
    const float* __restrict__ attn_bias, float* __restrict__ sw, int layer)
{
    __shared__ float aT[32][68];
    __shared__ float w_l[32][64];
    int tid = threadIdx.x;
    int m0 = blockIdx.x * 64;               // row = (b*NN + n)*8 + h
    int tx = tid & 15, ty = tid >> 4;
    {
        int row = tid >> 2, cb = (tid & 3) * 8;
        const float* ap = xm + (size_t)(m0 + row)*DHH + cb;
        float4 v0 = *(const float4*)ap, v1 = *(const float4*)(ap + 4);
        aT[cb+0][row] = v0.x; aT[cb+1][row] = v0.y; aT[cb+2][row] = v0.z; aT[cb+3][row] = v0.w;
        aT[cb+4][row] = v1.x; aT[cb+5][row] = v1.y; aT[cb+6][row] = v1.z; aT[cb+7][row] = v1.w;
        int kk = tid >> 3, seg = tid & 7;
        const float* wsrc = (seg < 4) ? (pt_w1 + layer*DHH*GG + kk*GG + seg*8)
                                      : (ps_w  + layer*DHH*GG + kk*GG + (seg-4)*8);
        *(float4*)&w_l[kk][seg*8]     = *(const float4*)wsrc;
        *(float4*)&w_l[kk][seg*8 + 4] = *(const float4*)(wsrc + 4);
    }
    __syncthreads();
    float acc[4][4];
    #pragma unroll
    for (int i = 0; i < 4; ++i)
        #pragma unroll
        for (int j = 0; j < 4; ++j) acc[i][j] = 0.f;
    #pragma unroll
    for (int k = 0; k < 32; ++k) {
        float4 av = *(const float4*)&aT[k][ty*4];
        float4 wv = *(const float4*)&w_l[k][tx*4];
        acc[0][0] += av.x*wv.x; acc[0][1] += av.x*wv.y; acc[0][2] += av.x*wv.z; acc[0][3] += av.x*wv.w;
        acc[1][0] += av.y*wv.x; acc[1][1] += av.y*wv.y; acc[1][2] += av.y*wv.z; acc[1][3] += av.y*wv.w;
        acc[2][0] += av.z*wv.x; acc[2][1] += av.z*wv.y; acc[2][2] += av.z*wv.z; acc[2][3] += av.z*wv.w;
        acc[3][0] += av.w*wv.x; acc[3][1] += av.w*wv.y; acc[3][2] += av.w*wv.z; acc[3][3] += av.w*wv.w;
    }
    int mbase = m0 + ty*4;
    float s[4] = {0.f, 0.f, 0.f, 0.f};
    if (tx < 8) {
        float4 b1 = *(const float4*)(pt_b1 + layer*GG + tx*4);
        float4 w2 = *(const float4*)(pt_w2 + layer*GG + tx*4);
        #pragma unroll
        for (int mi = 0; mi < 4; ++mi) {
            s[mi] = gelu_f(acc[mi][0] + b1.x) * w2.x + gelu_f(acc[mi][1] + b1.y) * w2.y
                  + gelu_f(acc[mi][2] + b1.z) * w2.z + gelu_f(acc[mi][3] + b1.w) * w2.w;
        }
    }
    #pragma unroll
    for (int mi = 0; mi < 4; ++mi) {
        #pragma unroll
        for (int off = 1; off <= 4; off <<= 1) s[mi] += __shfl_xor(s[mi], off);
        s[mi] += __shfl_xor(s[mi], 8);   // broadcast to high half
    }
    float ptb2 = pt_b2[layer];
    if (tx >= 8) {
        int g0 = (tx - 8) * 4;
        float4 psb = *(const float4*)(ps_b + layer*GG + g0);
        float ev[4][4], mx[4], sm[4];
        #pragma unroll
        for (int mi = 0; mi < 4; ++mi) {
            int row = mbase + mi;
            int h = row & 7, n = (row >> 3) & (NN - 1), b = row >> 17;  // NN*8 = 2^17
            float ab = attn_bias[layer*HH + h];
            float rt = 1.f / fmaxf(gelu_f(s[mi] + ptb2) + ab, 0.01f);
            float4 gv = *(const float4*)(gumbel +
                ((((size_t)layer*BB + b)*HH + h)*NN + n)*GG + g0);
            float l0 = (acc[mi][0] + psb.x - __logf(-__logf(gv.x + 1e-8f) + 1e-8f)) * rt;
            float l1 = (acc[mi][1] + psb.y - __logf(-__logf(gv.y + 1e-8f) + 1e-8f)) * rt;
            float l2 = (acc[mi][2] + psb.z - __logf(-__logf(gv.z + 1e-8f) + 1e-8f)) * rt;
            float l3 = (acc[mi][3] + psb.w - __logf(-__logf(gv.w + 1e-8f) + 1e-8f)) * rt;
            float m01 = fmaxf(l0, l1), m23 = fmaxf(l2, l3);
            mx[mi] = fmaxf(m01, m23);
            ev[mi][0] = l0; ev[mi][1] = l1; ev[mi][2] = l2; ev[mi][3] = l3;
        }
        #pragma unroll
        for (int mi = 0; mi < 4; ++mi) {
            #pragma unroll
            for (int off = 1; off <= 4; off <<= 1) mx[mi] = fmaxf(mx[mi], __shfl_xor(mx[mi], off));
            float e0 = __expf(ev[mi][0] - mx[mi]);
            float e1 = __expf(ev[mi][1] - mx[mi]);
            float e2 = __expf(ev[mi][2] - mx[mi]);
            float e3 = __expf(ev[mi][3] - mx[mi]);
            ev[mi][0] = e0; ev[mi][1] = e1; ev[mi][2] = e2; ev[mi][3] = e3;
            sm[mi] = e0 + e1 + e2 + e3;
            #pragma unroll
            for (int off = 1; off <= 4; off <<= 1) sm[mi] += __shfl_xor(sm[mi], off);
        }
        #pragma unroll
        for (int mi = 0; mi < 4; ++mi) {
            int row = mbase + mi;
            int h = row & 7, n = (row >> 3) & (NN - 1), b = row >> 17;
            float inv = 1.f / sm[mi];
            *(float4*)(sw + (((size_t)(b*HH + h))*NN + n)*GG + g0) =
                make_float4(ev[mi][0]*inv, ev[mi][1]*inv, ev[mi][2]*inv, ev[mi][3]*inv);
        }
    }
}

// ---------------------------------------------------------------------------
// k_st: st[bh][g][c] = sum_n sw[bh][n][g]*xm[b][n][h*32+c]; nrm = sum sw.
// ---------------------------------------------------------------------------
__global__ __launch_bounds__(256) void k_st(
    const float* __restrict__ sw, const float* __restrict__ xm,
    float* __restrict__ st, float* __restrict__ nrm)
{
    __shared__ float sw_l[1024];
    __shared__ float xm_l[1024];
    __shared__ float part[4096];
    int tid = threadIdx.x;
    int bh = blockIdx.x >> 4;
    int b = bh >> 3, h = bh & 7;
    int n0 = (blockIdx.x & 15) << 10;
    int w = tid >> 6, lane = tid & 63;
    int g0 = (lane & 7) * 4, c0 = (lane >> 3) * 4;
    int row = tid >> 3, col4 = (tid & 7) * 4;
    float acc[4][4];
    #pragma unroll
    for (int i = 0; i < 4; ++i)
        #pragma unroll
        for (int j = 0; j < 4; ++j) acc[i][j] = 0.f;
    float nacc[4] = {0.f, 0.f, 0.f, 0.f};

    for (int t8 = 0; t8 < 32; ++t8) {
        int nb = n0 + t8*32;
        *(float4*)&sw_l[tid*4] = ((const float4*)(sw + ((size_t)bh*NN + nb)*GG))[tid];
        *(float4*)&xm_l[tid*4] = *(const float4*)(xm + (size_t)(b*NN + nb + row)*HID + h*DHH + col4);
        __syncthreads();
        #pragma unroll
        for (int tt = 0; tt < 8; ++tt) {
            int t = w*8 + tt;
            float4 a  = *(float4*)&sw_l[t*32 + g0];
            float4 xv = *(float4*)&xm_l[t*32 + c0];
            acc[0][0] += a.x*xv.x; acc[0][1] += a.x*xv.y; acc[0][2] += a.x*xv.z; acc[0][3] += a.x*xv.w;
            acc[1][0] += a.y*xv.x; acc[1][1] += a.y*xv.y; acc[1][2] += a.y*xv.z; acc[1][3] += a.y*xv.w;
            acc[2][0] += a.z*xv.x; acc[2][1] += a.z*xv.y; acc[2][2] += a.z*xv.z; acc[2][3] += a.z*xv.w;
            acc[3][0] += a.w*xv.x; acc[3][1] += a.w*xv.y; acc[3][2] += a.w*xv.z; acc[3][3] += a.w*xv.w;
            nacc[0] += a.x; nacc[1] += a.y; nacc[2] += a.z; nacc[3] += a.w;
        }
        __syncthreads();
    }
    #pragma unroll
    for (int i = 0; i < 4; ++i)
        *(float4*)&part[w*1024 + (g0+i)*32 + c0] =
            make_float4(acc[i][0], acc[i][1], acc[i][2], acc[i][3]);
    __syncthreads();
    #pragma unroll
    for (int r = 0; r < 4; ++r) {
        int idx = r*256 + tid;
        float v = part[idx] + part[1024+idx] + part[2048+idx] + part[3072+idx];
        atomicAdd(&st[(size_t)bh*GG*DHH + idx], v);
    }
    if ((lane >> 3) == 0) {
        #pragma unroll
        for (int i = 0; i < 4; ++i)
            atomicAdd(&nrm[bh*GG + g0 + i], nacc[i]);
    }
}

// ---------------------------------------------------------------------------
// B: slice-token attention per (b,h). grid = B*H = 32 blocks.
// ---------------------------------------------------------------------------
__global__ __launch_bounds__(256) void k_b(
    const float* __restrict__ st, const float* __restrict__ nrm,
    const float* __restrict__ q_w, const float* __restrict__ k_w, const float* __restrict__ v_w,
    float* __restrict__ o, int layer)
{
    __shared__ float st_l[32][33], q_l[32][33], k_l[32][33], v_l[32][33], a_l[32][33];
    __shared__ float wq[32][32], wk[32][32], wv[32][32];
    int tid = threadIdx.x;
    int bh = blockIdx.x;
    #pragma unroll
    for (int r = 0; r < 4; ++r) {
        ((float*)wq)[r*256 + tid] = q_w[(size_t)layer*DHH*DHH + r*256 + tid];
        ((float*)wk)[r*256 + tid] = k_w[(size_t)layer*DHH*DHH + r*256 + tid];
        ((float*)wv)[r*256 + tid] = v_w[(size_t)layer*DHH*DHH + r*256 + tid];
    }
    #pragma unroll
    for (int r = 0; r < 4; ++r) {
        int idx = r*256 + tid;
        int gg2 = idx >> 5, cc = idx & 31;
        st_l[gg2][cc] = st[(size_t)bh*GG*DHH + idx] / (nrm[bh*GG + gg2] + 1e-5f);
    }
    __syncthreads();
    int g2 = tid >> 3, c4 = (tid & 7) * 4;
    float aq[4] = {0,0,0,0}, ak[4] = {0,0,0,0}, avv[4] = {0,0,0,0};
    #pragma unroll
    for (int k = 0; k < 32; ++k) {
        float sv = st_l[g2][k];
        #pragma unroll
        for (int j = 0; j < 4; ++j) {
            aq[j]  += sv * wq[k][c4+j];
            ak[j]  += sv * wk[k][c4+j];
            avv[j] += sv * wv[k][c4+j];
        }
    }
    #pragma unroll
    for (int j = 0; j < 4; ++j) { q_l[g2][c4+j] = aq[j]; k_l[g2][c4+j] = ak[j]; v_l[g2][c4+j] = avv[j]; }
    __syncthreads();
    if (tid < 32) {
        int gq = tid;
        float sc[32];
        float mx = -1e30f;
        #pragma unroll
        for (int j = 0; j < 32; ++j) {
            float s2 = 0.f;
            #pragma unroll
            for (int c = 0; c < 32; ++c) s2 += q_l[gq][c] * k_l[j][c];
            s2 *= 0.17677669529663687f;  // 1/sqrt(32)
            sc[j] = s2;
            mx = fmaxf(mx, s2);
        }
        float se = 0.f;
        #pragma unroll
        for (int j = 0; j < 32; ++j) { sc[j] = __expf(sc[j] - mx); se += sc[j]; }
        float inv = 1.f / se;
        #pragma unroll
        for (int j = 0; j < 32; ++j) a_l[gq][j] = sc[j] * inv;
    }
    __syncthreads();
    float ao[4] = {0,0,0,0};
    #pragma unroll
    for (int k2 = 0; k2 < 32; ++k2) {
        float aw = a_l[g2][k2];
        #pragma unroll
        for (int j = 0; j < 4; ++j) ao[j] += aw * v_l[k2][c4+j];
    }
    #pragma unroll
    for (int j = 0; j < 4; ++j) o[(size_t)bh*GG*DHH + g2*DHH + c4 + j] = ao[j];
}

// ---------------------------------------------------------------------------
// ox scatter-back -> bf16: oxh[n, h*32+c] = bf16(sum_g o[b,h,g,c]*sw[b,h,n,g])
// ---------------------------------------------------------------------------
__global__ __launch_bounds__(256) void k_ox(
    const float* __restrict__ sw, const float* __restrict__ o, ushort* __restrict__ oxh)
{
    __shared__ float o_l[8192];
    __shared__ float sw_l[16][256];
    int tid = threadIdx.x;
    int m0 = blockIdx.x * 64;
    int b = m0 / NN;
    int n0 = m0 % NN;
    int h = tid >> 5, c = tid & 31;
    #pragma unroll
    for (int r = 0; r < 32; ++r) o_l[r*256 + tid] = o[(size_t)b*HH*GG*DHH + r*256 + tid];
    __syncthreads();
    for (int mc = 0; mc < 4; ++mc) {
        #pragma unroll
        for (int r = 0; r < 16; ++r)
            sw_l[r][tid] = sw[(size_t)((b*HH + h)*NN + n0 + mc*16 + r)*GG + c];
        __syncthreads();
        for (int ml = 0; ml < 16; ++ml) {
            float acc2 = 0.f;
            #pragma unroll
            for (int gg2 = 0; gg2 < 32; ++gg2)
                acc2 += sw_l[ml][h*32 + gg2] * o_l[(h*32 + gg2)*32 + c];
            oxh[(size_t)(m0 + mc*16 + ml)*HID + tid] = (ushort)f2b(acc2);
        }
        __syncthreads();
    }
}

// ---------------------------------------------------------------------------
// Head: out = LN3(fx) @ head_w + head_b. grid NT/64.
// ---------------------------------------------------------------------------
__global__ __launch_bounds__(256) void k_head(
    const float* __restrict__ fx, const float* __restrict__ mu, const float* __restrict__ rstd,
    const float* __restrict__ g3, const float* __restrict__ b3,
    const float* __restrict__ hw, const float* __restrict__ hb,
    float* __restrict__ out)
{
    __shared__ float fx_l[64][257];
    int tid = threadIdx.x;
    int m0 = blockIdx.x * 64;
    for (int r = 0; r < 64; ++r) fx_l[r][tid] = fx[(size_t)(m0 + r)*HID + tid];
    __syncthreads();
    int ml = tid & 63, oo = tid >> 6;
    float mu_ = mu[m0 + ml], rs_ = rstd[m0 + ml];
    float acc2 = hb[oo];
    #pragma unroll 8
    for (int k = 0; k < HID; ++k) {
        float hv = (fx_l[ml][k] - mu_) * rs_ * g3[k] + b3[k];
        acc2 += hv * hw[k*4 + oo];
    }
    out[(size_t)(m0 + ml)*4 + oo] = acc2;
}

// ---------------------------------------------------------------------------
extern "C" void kernel_launch(void* const* d_in, const int* in_sizes, int n_in,
                              void* d_out, int out_size, void* d_ws, size_t ws_size,
                              hipStream_t stream)
{
    (void)in_sizes; (void)n_in; (void)out_size; (void)ws_size;
    const float* x          = (const float*)d_in[0];
    const float* condition  = (const float*)d_in[1];
    const float* gumbel     = (const float*)d_in[2];
    const float* pre_w1     = (const float*)d_in[3];
    const float* pre_b1     = (const float*)d_in[4];
    const float* pre_w2     = (const float*)d_in[5];
    const float* pre_b2     = (const float*)d_in[6];
    const float* placeholder= (const float*)d_in[7];
    const float* emb_w      = (const float*)d_in[8];
    const float* emb_b      = (const float*)d_in[9];
    const float* ln1_g      = (const float*)d_in[10];
    const float* ln1_b      = (const float*)d_in[11];
    const float* attn_bias  = (const float*)d_in[12];
    const float* pt_w1      = (const float*)d_in[13];
    const float* pt_b1      = (const float*)d_in[14];
    const float* pt_w2      = (const float*)d_in[15];
    const float* pt_b2      = (const float*)d_in[16];
    const float* px_w       = (const float*)d_in[17];
    const float* px_b       = (const float*)d_in[18];
    const float* ps_w       = (const float*)d_in[19];
    const float* ps_b       = (const float*)d_in[20];
    const float* q_w        = (const float*)d_in[21];
    const float* k_w        = (const float*)d_in[22];
    const float* v_w        = (const float*)d_in[23];
    const float* o_w        = (const float*)d_in[24];
    const float* o_b        = (const float*)d_in[25];
    const float* ln2_g      = (const float*)d_in[26];
    const float* ln2_b      = (const float*)d_in[27];
    const float* mlp_w1     = (const float*)d_in[28];
    const float* mlp_b1     = (const float*)d_in[29];
    const float* mlp_w2     = (const float*)d_in[30];
    const float* mlp_b2     = (const float*)d_in[31];
    const float* ln3_g      = (const float*)d_in[32];
    const float* ln3_b      = (const float*)d_in[33];
    const float* head_w     = (const float*)d_in[34];
    const float* head_b     = (const float*)d_in[35];

    float* ws   = (float*)d_ws;
    float* fx   = ws;                                   // NT*HID fp32
    float* xm   = fx  + (size_t)NT*HID;                 // NT*HID fp32 (overlaid by oxh/th)
    float* sw   = xm  + (size_t)NT*HID;                 // B*H*N*G fp32
    float* mu   = sw  + (size_t)BB*HH*NN*GG;            // NT
    float* rstd = mu  + NT;                             // NT
    float* st   = rstd+ NT;                             // 32768
    float* nrm  = st  + BB*HH*GG*DHH;                   // 1024
    float* o    = nrm + BB*HH*GG;                       // 32768
    ushort* fxh = (ushort*)(o + BB*HH*GG*DHH);          // NT*HID bf16
    ushort* wq  = fxh + (size_t)NT*HID;                 // 10 * 65536 (px/mlp1 LN-folded)
    ushort* wo  = wq  + 10*65536;                       // 5 * 65536
    ushort* wm2 = wo  + 5*65536;                        // 5 * 65536
    ushort* wpre= wm2 + 5*65536;                        // 131072 (pre_w2, K=512)
    float* ucst = (float*)(wpre + 131072);              // 10 * 512 (u|cst)
    // overlays on xm region (timeline-disjoint): oxh after k_st, th after o_w GEMM
    ushort* oxh = (ushort*)xm;
    ushort* th  = (ushort*)xm + (size_t)NT*HID;

    dim3 blk(256);
    k_wprep<<<10, blk, 0, stream>>>(px_w, px_b, ln1_g, ln1_b, mlp_w1, mlp_b1, ln2_g, ln2_b, wq, ucst);
    k_wcvt<<<96, blk, 0, stream>>>(o_w, mlp_w2, pre_w2, wo, wm2, wpre);
    k_pre_mf<<<NT/64, blk, 0, stream>>>(x, condition, pre_w1, pre_b1, wpre, pre_b2,
                                        placeholder, emb_w, emb_b, fx);
    for (int i = 0; i < LL; ++i) {
        k_stats_cast<<<NT/64, blk, 0, stream>>>(fx, mu, rstd, fxh);
        k_zero<<<(33792 + 255)/256, blk, 0, stream>>>(st, 33792);
        k_mf<<<NT/64, blk, 0, stream>>>(fxh, wq + (size_t)(2*i)*65536, xm, nullptr,
                                        mu, rstd, ucst + (2*i)*512, ucst + (2*i)*512 + 256,
                                        nullptr, nullptr, 0);
        k_pt<<<NT*HH/64, blk, 0, stream>>>(xm, gumbel, pt_w1, pt_b1, pt_w2, pt_b2,
                                           ps_w, ps_b, attn_bias, sw, i);
        k_st<<<BB*HH*16, blk, 0, stream>>>(sw, xm, st, nrm);
        k_b<<<BB*HH, blk, 0, stream>>>(st, nrm, q_w, k_w, v_w, o, i);
        k_ox<<<NT/64, blk, 0, stream>>>(sw, o, oxh);
        k_mf<<<NT/64, blk, 0, stream>>>(oxh, wo + (size_t)i*65536, fx, nullptr,
                                        nullptr, nullptr, nullptr, nullptr,
                                        o_b + i*HID, fx, 2);
        k_stats_cast<<<NT/64, blk, 0, stream>>>(fx, mu, rstd, fxh);
        k_mf<<<NT/64, blk, 0, stream>>>(fxh, wq + (size_t)(2*i+1)*65536, nullptr, th,
                                        mu, rstd, ucst + (2*i+1)*512, ucst + (2*i+1)*512 + 256,
                                        nullptr, nullptr, 1);
        k_mf<<<NT/64, blk, 0, stream>>>(th, wm2 + (size_t)i*65536, fx, nullptr,
                                        nullptr, nullptr, nullptr, nullptr,
                                        mlp_b2 + i*HID, fx, 2);
    }
    k_stats_cast<<<NT/64, blk, 0, stream>>>(fx, mu, rstd, fxh);
    k_head<<<NT/64, blk, 0, stream>>>(fx, mu, rstd, ln3_g, ln3_b, head_w, head_b, (float*)d_out);
}